// Round 4
// baseline (355.546 us; speedup 1.0000x reference)
//
#include <hip/hip_runtime.h>
#include <hip/hip_fp16.h>
#include <math.h>

#define FEAT 128
#define HID  64
#define BSH  7                 // 128 dst-nodes per bucket
#define BNODES (1 << BSH)
#define PB   256               // partition blocks
#define SRCM ((1u << 25) - 1)  // src in low 25 bits, dst_local in high 7
#define SL   4                 // feature slices (4 planes of 16 feats = 3.2MB, fits 4MB XCD L2)

// ---------------- stage 1: edge partition by dst-bucket ----------------

__global__ void part_hist_k(const int* __restrict__ dst, int* __restrict__ table,
                            int e, int nb) {
    __shared__ int lcnt[1024];
    for (int i = threadIdx.x; i < nb; i += 256) lcnt[i] = 0;
    __syncthreads();
    int eb = (e + PB - 1) / PB;
    int lo = blockIdx.x * eb, hi = min(lo + eb, e);
    for (int i = lo + threadIdx.x; i < hi; i += 256)
        atomicAdd(&lcnt[dst[i] >> BSH], 1);
    __syncthreads();
    for (int k = threadIdx.x; k < nb; k += 256)
        table[k * PB + blockIdx.x] = lcnt[k];
}

__global__ void scan1_k(int* __restrict__ data, int* __restrict__ aux, int L) {
    __shared__ int s[1024];
    int gid = blockIdx.x * 1024 + threadIdx.x;
    int v = (gid < L) ? data[gid] : 0;
    s[threadIdx.x] = v;
    __syncthreads();
    for (int off = 1; off < 1024; off <<= 1) {
        int t = (threadIdx.x >= off) ? s[threadIdx.x - off] : 0;
        __syncthreads();
        s[threadIdx.x] += t;
        __syncthreads();
    }
    if (gid < L) data[gid] = s[threadIdx.x] - v;            // exclusive in block
    if (threadIdx.x == 1023) aux[blockIdx.x] = s[1023];     // block total
}

__global__ void scan2_k(int* aux, int naux) {
    __shared__ int s[1024];
    int v = (threadIdx.x < naux) ? aux[threadIdx.x] : 0;
    s[threadIdx.x] = v;
    __syncthreads();
    for (int off = 1; off < 1024; off <<= 1) {
        int t = (threadIdx.x >= off) ? s[threadIdx.x - off] : 0;
        __syncthreads();
        s[threadIdx.x] += t;
        __syncthreads();
    }
    if (threadIdx.x < naux) aux[threadIdx.x] = s[threadIdx.x] - v;
}

__global__ void part_scatter_k(const int* __restrict__ src, const int* __restrict__ dst,
                               const int* __restrict__ table, const int* __restrict__ aux,
                               unsigned* __restrict__ packed, int e, int nb) {
    __shared__ int loff[1024];
    for (int k = threadIdx.x; k < nb; k += 256) {
        int idx = k * PB + blockIdx.x;
        loff[k] = table[idx] + aux[idx >> 10];
    }
    __syncthreads();
    int eb = (e + PB - 1) / PB;
    int lo = blockIdx.x * eb, hi = min(lo + eb, e);
    for (int i = lo + threadIdx.x; i < hi; i += 256) {
        int d = dst[i];
        int p = atomicAdd(&loff[d >> BSH], 1);
        packed[p] = ((unsigned)(d & (BNODES - 1)) << 25) | (unsigned)src[i];
    }
}

// ---------------- stage 2: per-bucket counting sort -> per-node CSR + dinv ----

__global__ void bucket_sort_k(const unsigned* __restrict__ packed,
                              const int* __restrict__ table, const int* __restrict__ aux,
                              int* __restrict__ col, int* __restrict__ rowptr,
                              float* __restrict__ dinv, int n, int e, int nb) {
    __shared__ int cnt[BNODES];
    __shared__ int s[BNODES];
    __shared__ int cur[BNODES];
    const int k = blockIdx.x;
    const int t = threadIdx.x;
    if (t < BNODES) cnt[t] = 0;
    __syncthreads();
    int i0 = k * PB;
    int i1 = (k + 1) * PB;
    const int bs = table[i0] + aux[i0 >> 10];
    const int be = (k + 1 < nb) ? (table[i1] + aux[i1 >> 10]) : e;
    for (int i = bs + t; i < be; i += 256)
        atomicAdd(&cnt[packed[i] >> 25], 1);
    __syncthreads();
    if (t < BNODES) s[t] = cnt[t];
    __syncthreads();
    for (int off = 1; off < BNODES; off <<= 1) {
        int v = (t < BNODES && t >= off) ? s[t - off] : 0;
        __syncthreads();
        if (t < BNODES) s[t] += v;
        __syncthreads();
    }
    if (t < BNODES) {
        int base = bs + s[t] - cnt[t];
        cur[t] = base;
        int node = (k << BSH) + t;
        if (node < n) {
            rowptr[node] = base;
            dinv[node] = 1.0f / sqrtf(1.0f + (float)cnt[t]);
            if (node == n - 1) rowptr[n] = base + cnt[t];
        }
    }
    __syncthreads();
    for (int i = bs + t; i < be; i += 256) {
        unsigned u = packed[i];
        int p = atomicAdd(&cur[u >> 25], 1);
        col[p] = (int)(u & SRCM);
    }
}

// ---------------- dense transform -> SLICED fp16 planes ----------------
// out layout: plane p (p=0..3) at out + p*n*16 halves; row = 16 halves (32B).
// IN16: input is sliced fp16 planes (from previous gather).

template<int K, bool IN16>
__global__ __launch_bounds__(256, (K == 128) ? 3 : 4)
void gemm_tile_k(const void* __restrict__ Xv, const float* __restrict__ W,
                 const float* __restrict__ dinv, __half* __restrict__ out, int n) {
    __shared__ float sX[64][K + 4];
    __shared__ float sW[64][64];       // one 64-row slab of W
    const int row0 = blockIdx.x * 64;
    const int t  = threadIdx.x;
    const int tx = t & 15;
    const int ty = t >> 4;
    constexpr int KSH = (K == 128) ? 7 : 6;

    if constexpr (!IN16) {
        const float* xb = (const float*)Xv + (size_t)row0 * K;
#pragma unroll
        for (int it = 0; it < K / 16; ++it) {
            int fl = it * 1024 + t * 4;
            int r  = fl >> KSH;
            int k  = fl & (K - 1);
            float4 v = make_float4(0.f, 0.f, 0.f, 0.f);
            if (row0 + r < n) v = *(const float4*)(xb + fl);
            *(float4*)&sX[r][k] = v;
        }
    } else {
        // sliced fp16 input (K==64): thread loads 8 halves (16B) from one plane
        const __half* xb = (const __half*)Xv;
#pragma unroll
        for (int it = 0; it < K / 32; ++it) {
            int fl = it * 2048 + t * 8;    // half-index within 64x64 tile
            int r  = fl >> 6;
            int k  = fl & 63;
            int plane = k >> 4;
            int off   = k & 15;
            float4 raw = make_float4(0.f, 0.f, 0.f, 0.f);
            if (row0 + r < n)
                raw = *(const float4*)(xb + ((size_t)plane * n + row0 + r) * 16 + off);
            const __half2* hp = (const __half2*)&raw;
#pragma unroll
            for (int j = 0; j < 4; ++j) {
                float2 f = __half22float2(hp[j]);
                sX[r][k + 2 * j]     = f.x;
                sX[r][k + 2 * j + 1] = f.y;
            }
        }
    }

    float acc[4][4] = {};
#pragma unroll
    for (int ph = 0; ph < K / 64; ++ph) {
        __syncthreads();
#pragma unroll
        for (int it = 0; it < 4; ++it) {
            int fl = it * 1024 + t * 4;
            *(float4*)&sW[fl >> 6][fl & 63] = *(const float4*)(W + ph * 64 * HID + fl);
        }
        __syncthreads();

#pragma unroll 8
        for (int k = 0; k < 64; k += 4) {
            float4 a[4], b[4];
#pragma unroll
            for (int i = 0; i < 4; i++) a[i] = *(float4*)&sX[ty * 4 + i][ph * 64 + k];
#pragma unroll
            for (int j = 0; j < 4; j++) b[j] = *(float4*)&sW[k + j][tx * 4];
#pragma unroll
            for (int i = 0; i < 4; i++) {
                acc[i][0] = fmaf(a[i].x, b[0].x, acc[i][0]);
                acc[i][1] = fmaf(a[i].x, b[0].y, acc[i][1]);
                acc[i][2] = fmaf(a[i].x, b[0].z, acc[i][2]);
                acc[i][3] = fmaf(a[i].x, b[0].w, acc[i][3]);
                acc[i][0] = fmaf(a[i].y, b[1].x, acc[i][0]);
                acc[i][1] = fmaf(a[i].y, b[1].y, acc[i][1]);
                acc[i][2] = fmaf(a[i].y, b[1].z, acc[i][2]);
                acc[i][3] = fmaf(a[i].y, b[1].w, acc[i][3]);
                acc[i][0] = fmaf(a[i].z, b[2].x, acc[i][0]);
                acc[i][1] = fmaf(a[i].z, b[2].y, acc[i][1]);
                acc[i][2] = fmaf(a[i].z, b[2].z, acc[i][2]);
                acc[i][3] = fmaf(a[i].z, b[2].w, acc[i][3]);
                acc[i][0] = fmaf(a[i].w, b[3].x, acc[i][0]);
                acc[i][1] = fmaf(a[i].w, b[3].y, acc[i][1]);
                acc[i][2] = fmaf(a[i].w, b[3].z, acc[i][2]);
                acc[i][3] = fmaf(a[i].w, b[3].w, acc[i][3]);
            }
        }
    }

    // epilogue: features tx*4..tx*4+3 -> plane tx>>2, half-offset (tx&3)*4
#pragma unroll
    for (int i = 0; i < 4; i++) {
        int gr = row0 + ty * 4 + i;
        if (gr < n) {
            float sc = dinv[gr];
            union { __half2 h[2]; unsigned long long u; } pk;
            pk.h[0] = __floats2half2_rn(acc[i][0] * sc, acc[i][1] * sc);
            pk.h[1] = __floats2half2_rn(acc[i][2] * sc, acc[i][3] * sc);
            __half* pl = out + ((size_t)(tx >> 2) * n + gr) * 16 + (tx & 3) * 4;
            *(unsigned long long*)pl = pk.u;
        }
    }
}

// ---------------- sliced CSR gather ----------------
// slice = blockIdx & 3 -> XCD x always sees plane x%4 (round-robin dispatch):
// per-XCD random-read working set = 3.2MB < 4MB L2. 8 lanes per node (16 feats),
// 32 nodes per block. out written in sliced layout. LOGITS: per-slice partial
// dot with Wa, atomicAdd to distinct logits[node] (zero-init'd).

template<bool LOGITS>
__global__ void gather_k(const __half* __restrict__ tS, const int* __restrict__ rowptr,
                         const int* __restrict__ col, const float* __restrict__ dinv,
                         const float* __restrict__ b, __half* __restrict__ out,
                         const float* __restrict__ Wa, const float* __restrict__ ba,
                         float* __restrict__ logits, int n) {
    const int slice = blockIdx.x & (SL - 1);
    const int chunk = blockIdx.x >> 2;
    const int nl = threadIdx.x >> 3;      // 0..31
    const int l8 = threadIdx.x & 7;       // lane in 8-lane group
    const int node = chunk * 32 + nl;
    if (node >= n) return;
    const int fp = slice * 8 + l8;        // feature-pair index (half2)

    int beg = rowptr[node], end = rowptr[node + 1];
    const __half2* tp = (const __half2*)tS + (size_t)slice * n * 8 + l8;
    float2 acc = __half22float2(tp[node * 8]);      // self-loop term
    int e = beg;
    for (; e + 16 <= end; e += 16) {
        int s[16];
        __half2 v[16];
#pragma unroll
        for (int j = 0; j < 16; j++) s[j] = __builtin_nontemporal_load(col + e + j);
#pragma unroll
        for (int j = 0; j < 16; j++) v[j] = tp[s[j] * 8];
        float2 t0 = make_float2(0.f, 0.f), t1 = make_float2(0.f, 0.f);
#pragma unroll
        for (int j = 0; j < 8; j++) {
            float2 f = __half22float2(v[j]);
            t0.x += f.x; t0.y += f.y;
        }
#pragma unroll
        for (int j = 8; j < 16; j++) {
            float2 f = __half22float2(v[j]);
            t1.x += f.x; t1.y += f.y;
        }
        acc.x += t0.x + t1.x;
        acc.y += t0.y + t1.y;
    }
    for (; e + 4 <= end; e += 4) {
        __half2 v0 = tp[col[e] * 8];
        __half2 v1 = tp[col[e + 1] * 8];
        __half2 v2 = tp[col[e + 2] * 8];
        __half2 v3 = tp[col[e + 3] * 8];
        float2 f0 = __half22float2(v0), f1 = __half22float2(v1);
        float2 f2 = __half22float2(v2), f3 = __half22float2(v3);
        acc.x += (f0.x + f1.x) + (f2.x + f3.x);
        acc.y += (f0.y + f1.y) + (f2.y + f3.y);
    }
    for (; e < end; ++e) {
        float2 f = __half22float2(tp[col[e] * 8]);
        acc.x += f.x; acc.y += f.y;
    }
    float d = dinv[node];
    float2 bb = *(const float2*)(b + 2 * fp);
    float h0 = fmaxf(fmaf(d, acc.x, bb.x), 0.0f);
    float h1 = fmaxf(fmaf(d, acc.y, bb.y), 0.0f);
    __half2 hv = __floats2half2_rn(h0, h1);
    unsigned int* op = (unsigned int*)((__half2*)out + (size_t)slice * n * 8 + node * 8 + l8);
    union { __half2 h; unsigned int u; } cv; cv.h = hv;
    __builtin_nontemporal_store(cv.u, op);
    if (LOGITS) {
        float2 wa = *(const float2*)(Wa + 2 * fp);
        float p = h0 * wa.x + h1 * wa.y;
        p += __shfl_down(p, 4, 8);
        p += __shfl_down(p, 2, 8);
        p += __shfl_down(p, 1, 8);
        if (l8 == 0) atomicAdd(&logits[node], p + (slice == 0 ? ba[0] : 0.0f));
    }
}

// ---------------- mean-pool partials (sliced, run-length batched) ----------------

__global__ void pool_k(const __half* __restrict__ h, const int* __restrict__ batch,
                       float* __restrict__ pooled, int n) {
    const int slice = blockIdx.x & (SL - 1);
    const int grp = (blockIdx.x >> 2) * 32 + (threadIdx.x >> 3);
    const int l8 = threadIdx.x & 7;
    int start = grp * 32;
    if (start >= n) return;
    int end = min(start + 32, n);
    const __half2* hp = (const __half2*)h + (size_t)slice * n * 8 + l8;
    const int fbase = 2 * (slice * 8 + l8);
    float2 acc = make_float2(0.f, 0.f);
    int curg = -1;
    for (int i = start; i < end; i++) {
        int g = batch[i];
        if (g != curg) {
            if (curg >= 0) {
                atomicAdd(&pooled[curg * HID + fbase], acc.x);
                atomicAdd(&pooled[curg * HID + fbase + 1], acc.y);
            }
            curg = g; acc = make_float2(0.f, 0.f);
        }
        float2 f = __half22float2(hp[i * 8]);
        acc.x += f.x; acc.y += f.y;
    }
    atomicAdd(&pooled[curg * HID + fbase], acc.x);
    atomicAdd(&pooled[curg * HID + fbase + 1], acc.y);
}

// ---------------- value head (counts via binary search on sorted batch) ----------------

__global__ void value_k(const float* __restrict__ pooled, const int* __restrict__ batch,
                        const float* __restrict__ Wc, const float* __restrict__ bc,
                        float* __restrict__ val, int n, int g) {
    int gw   = (int)((blockIdx.x * (size_t)blockDim.x + threadIdx.x) >> 6);
    int lane = threadIdx.x & 63;
    if (gw >= g) return;
    int lo = 0, hi = n;
    while (lo < hi) { int m = (lo + hi) >> 1; if (batch[m] < gw) lo = m + 1; else hi = m; }
    int b0 = lo;
    lo = 0; hi = n;
    while (lo < hi) { int m = (lo + hi) >> 1; if (batch[m] < gw + 1) lo = m + 1; else hi = m; }
    float cnt = fmaxf((float)(lo - b0), 1.0f);
    float p = (pooled[gw * HID + lane] / cnt) * Wc[lane];
#pragma unroll
    for (int off = 32; off > 0; off >>= 1) p += __shfl_down(p, off);
    if (lane == 0) val[gw] = p + bc[0];
}

extern "C" void kernel_launch(void* const* d_in, const int* in_sizes, int n_in,
                              void* d_out, int out_size, void* d_ws, size_t ws_size,
                              hipStream_t stream) {
    const float* x     = (const float*)d_in[0];
    const int*   ei    = (const int*)d_in[1];
    const int*   batch = (const int*)d_in[2];
    const float* W1    = (const float*)d_in[3];
    const float* b1    = (const float*)d_in[4];
    const float* W2    = (const float*)d_in[5];
    const float* b2    = (const float*)d_in[6];
    const float* Wa    = (const float*)d_in[7];
    const float* ba    = (const float*)d_in[8];
    const float* Wc    = (const float*)d_in[9];
    const float* bc    = (const float*)d_in[10];

    const int n = in_sizes[0] / FEAT;   // 100000
    const int e = in_sizes[1] / 2;      // 1600000
    const int g = out_size - n;         // 64
    const int* src = ei;
    const int* dst = ei + e;

    const int nb = (n + BNODES - 1) >> BSH;   // buckets (782)
    const int L  = nb * PB;                    // offset table length

    // workspace layout (packed aliases bufA: dead before first gemm)
    float*    ws     = (float*)d_ws;
    float*    dinv   = ws;                               // n
    float*    bufA   = dinv + n;                         // n*HID floats of space (tS fp16 sliced)
    float*    bufB   = bufA + (size_t)n * HID;           // n*HID floats of space (h fp16 sliced)
    float*    pooled = bufB + (size_t)n * HID;           // g*HID
    int*      table  = (int*)(pooled + (size_t)g * HID); // L
    int*      aux    = table + L;                        // 1024
    int*      rowptr = aux + 1024;                       // n+1
    int*      col    = rowptr + n + 1;                   // e
    unsigned* packed = (unsigned*)bufA;                  // e (aliased, transient)
    __half*   tS     = (__half*)bufA;                    // sliced planes
    __half*   h16    = (__half*)bufB;                    // sliced planes

    const int B = 256;
    const int gridT = (n + 63) / 64;
    const int gridG = ((n + 31) / 32) * SL;                  // 8-lane group per node-slice
    const int gridP = ((n + 32 * 32 - 1) / (32 * 32)) * SL;
    const int nb1   = (L + 1023) / 1024;

    hipMemsetAsync(pooled, 0, (size_t)g * HID * sizeof(float), stream);
    hipMemsetAsync(d_out, 0, (size_t)n * sizeof(float), stream);   // logits accumulated atomically

    // two-level CSR build: bucket partition -> in-bucket counting sort
    part_hist_k<<<PB, B, 0, stream>>>(dst, table, e, nb);
    scan1_k<<<nb1, 1024, 0, stream>>>(table, aux, L);
    scan2_k<<<1, 1024, 0, stream>>>(aux, nb1);
    part_scatter_k<<<PB, B, 0, stream>>>(src, dst, table, aux, packed, e, nb);
    bucket_sort_k<<<nb, B, 0, stream>>>(packed, table, aux, col, rowptr, dinv, n, e, nb);

    // layer 1
    gemm_tile_k<FEAT, false><<<gridT, B, 0, stream>>>(x, W1, dinv, tS, n);
    gather_k<false><<<gridG, B, 0, stream>>>(tS, rowptr, col, dinv, b1, h16,
                                             nullptr, nullptr, nullptr, n);

    // layer 2 (logits fused, accumulated across slices)
    gemm_tile_k<HID, true><<<gridT, B, 0, stream>>>(h16, W2, dinv, tS, n);
    gather_k<true><<<gridG, B, 0, stream>>>(tS, rowptr, col, dinv, b2, (__half*)bufB,
                                            Wa, ba, (float*)d_out, n);

    // heads
    pool_k<<<gridP, B, 0, stream>>>((__half*)bufB, batch, pooled, n);
    value_k<<<(g * 64 + B - 1) / B, B, 0, stream>>>(pooled, batch, Wc, bc,
                                                    (float*)d_out + n, n, g);
}

// Round 5
// 322.671 us; speedup vs baseline: 1.1019x; 1.1019x over previous
//
#include <hip/hip_runtime.h>
#include <hip/hip_fp16.h>
#include <math.h>

#define FEAT 128
#define HID  64
#define BSH  7                 // 128 dst-nodes per bucket
#define BNODES (1 << BSH)
#define PB   256               // partition blocks (256: full-chip parallelism)
#define SRCM ((1u << 25) - 1)  // src in low 25 bits, dst_local in high 7

// ---------------- stage 1: edge partition by dst-bucket ----------------

__global__ void part_hist_k(const int* __restrict__ dst, int* __restrict__ table,
                            int e, int nb) {
    __shared__ int lcnt[1024];
    for (int i = threadIdx.x; i < nb; i += 256) lcnt[i] = 0;
    __syncthreads();
    int eb = (e + PB - 1) / PB;
    int lo = blockIdx.x * eb, hi = min(lo + eb, e);
    for (int i = lo + threadIdx.x; i < hi; i += 256)
        atomicAdd(&lcnt[dst[i] >> BSH], 1);
    __syncthreads();
    for (int k = threadIdx.x; k < nb; k += 256)
        table[k * PB + blockIdx.x] = lcnt[k];
}

__global__ void scan1_k(int* __restrict__ data, int* __restrict__ aux, int L) {
    __shared__ int s[1024];
    int gid = blockIdx.x * 1024 + threadIdx.x;
    int v = (gid < L) ? data[gid] : 0;
    s[threadIdx.x] = v;
    __syncthreads();
    for (int off = 1; off < 1024; off <<= 1) {
        int t = (threadIdx.x >= off) ? s[threadIdx.x - off] : 0;
        __syncthreads();
        s[threadIdx.x] += t;
        __syncthreads();
    }
    if (gid < L) data[gid] = s[threadIdx.x] - v;            // exclusive in block
    if (threadIdx.x == 1023) aux[blockIdx.x] = s[1023];     // block total
}

__global__ void scan2_k(int* aux, int naux) {
    __shared__ int s[1024];
    int v = (threadIdx.x < naux) ? aux[threadIdx.x] : 0;
    s[threadIdx.x] = v;
    __syncthreads();
    for (int off = 1; off < 1024; off <<= 1) {
        int t = (threadIdx.x >= off) ? s[threadIdx.x - off] : 0;
        __syncthreads();
        s[threadIdx.x] += t;
        __syncthreads();
    }
    if (threadIdx.x < naux) aux[threadIdx.x] = s[threadIdx.x] - v;
}

__global__ void part_scatter_k(const int* __restrict__ src, const int* __restrict__ dst,
                               const int* __restrict__ table, const int* __restrict__ aux,
                               unsigned* __restrict__ packed, int e, int nb) {
    __shared__ int loff[1024];
    for (int k = threadIdx.x; k < nb; k += 256) {
        int idx = k * PB + blockIdx.x;
        loff[k] = table[idx] + aux[idx >> 10];
    }
    __syncthreads();
    int eb = (e + PB - 1) / PB;
    int lo = blockIdx.x * eb, hi = min(lo + eb, e);
    for (int i = lo + threadIdx.x; i < hi; i += 256) {
        int d = dst[i];
        int p = atomicAdd(&loff[d >> BSH], 1);
        packed[p] = ((unsigned)(d & (BNODES - 1)) << 25) | (unsigned)src[i];
    }
}

// ---------------- stage 2: per-bucket counting sort -> per-node CSR + dinv ----

__global__ void bucket_sort_k(const unsigned* __restrict__ packed,
                              const int* __restrict__ table, const int* __restrict__ aux,
                              int* __restrict__ col, int* __restrict__ rowptr,
                              float* __restrict__ dinv, int n, int e, int nb) {
    __shared__ int cnt[BNODES];
    __shared__ int s[BNODES];
    __shared__ int cur[BNODES];
    const int k = blockIdx.x;
    const int t = threadIdx.x;
    if (t < BNODES) cnt[t] = 0;
    __syncthreads();
    int i0 = k * PB;
    int i1 = (k + 1) * PB;
    const int bs = table[i0] + aux[i0 >> 10];
    const int be = (k + 1 < nb) ? (table[i1] + aux[i1 >> 10]) : e;
    for (int i = bs + t; i < be; i += 256)
        atomicAdd(&cnt[packed[i] >> 25], 1);
    __syncthreads();
    if (t < BNODES) s[t] = cnt[t];
    __syncthreads();
    for (int off = 1; off < BNODES; off <<= 1) {
        int v = (t < BNODES && t >= off) ? s[t - off] : 0;
        __syncthreads();
        if (t < BNODES) s[t] += v;
        __syncthreads();
    }
    if (t < BNODES) {
        int base = bs + s[t] - cnt[t];
        cur[t] = base;
        int node = (k << BSH) + t;
        if (node < n) {
            rowptr[node] = base;
            dinv[node] = 1.0f / sqrtf(1.0f + (float)cnt[t]);
            if (node == n - 1) rowptr[n] = base + cnt[t];
        }
    }
    __syncthreads();
    for (int i = bs + t; i < be; i += 256) {
        unsigned u = packed[i];
        int p = atomicAdd(&cur[u >> 25], 1);
        col[p] = (int)(u & SRCM);
    }
}

// ---------------- dense transform: out[n,64] = fp16((X[n,K] @ W[K,64]) * dinv[row]) ----
// IN16: input matrix stored fp16 row-major (layer 2 reads gather's fp16 h output)

template<int K, bool IN16>
__global__ __launch_bounds__(256, (K == 128) ? 3 : 4)
void gemm_tile_k(const void* __restrict__ Xv, const float* __restrict__ W,
                 const float* __restrict__ dinv, __half* __restrict__ out, int n) {
    __shared__ float sX[64][K + 4];
    __shared__ float sW[64][64];       // one 64-row slab of W
    const int row0 = blockIdx.x * 64;
    const int t  = threadIdx.x;
    const int tx = t & 15;
    const int ty = t >> 4;
    constexpr int KSH = (K == 128) ? 7 : 6;

    if constexpr (!IN16) {
        const float* xb = (const float*)Xv + (size_t)row0 * K;
#pragma unroll
        for (int it = 0; it < K / 16; ++it) {
            int fl = it * 1024 + t * 4;
            int r  = fl >> KSH;
            int k  = fl & (K - 1);
            float4 v = make_float4(0.f, 0.f, 0.f, 0.f);
            if (row0 + r < n) v = *(const float4*)(xb + fl);
            *(float4*)&sX[r][k] = v;
        }
    } else {
        // fp16 input, K==64: 64x64 halves; each thread loads 2x 16B (8 halves)
        const __half* xb = (const __half*)Xv + (size_t)row0 * K;
#pragma unroll
        for (int it = 0; it < K / 32; ++it) {
            int fl = it * 2048 + t * 8;    // half-index
            int r  = fl >> KSH;
            int k  = fl & (K - 1);
            float4 raw = make_float4(0.f, 0.f, 0.f, 0.f);
            if (row0 + r < n) raw = *(const float4*)(xb + fl);
            const __half2* hp = (const __half2*)&raw;
#pragma unroll
            for (int j = 0; j < 4; ++j) {
                float2 f = __half22float2(hp[j]);
                sX[r][k + 2 * j]     = f.x;
                sX[r][k + 2 * j + 1] = f.y;
            }
        }
    }

    float acc[4][4] = {};
#pragma unroll
    for (int ph = 0; ph < K / 64; ++ph) {
        __syncthreads();
#pragma unroll
        for (int it = 0; it < 4; ++it) {
            int fl = it * 1024 + t * 4;
            *(float4*)&sW[fl >> 6][fl & 63] = *(const float4*)(W + ph * 64 * HID + fl);
        }
        __syncthreads();

#pragma unroll 8
        for (int k = 0; k < 64; k += 4) {
            float4 a[4], b[4];
#pragma unroll
            for (int i = 0; i < 4; i++) a[i] = *(float4*)&sX[ty * 4 + i][ph * 64 + k];
#pragma unroll
            for (int j = 0; j < 4; j++) b[j] = *(float4*)&sW[k + j][tx * 4];
#pragma unroll
            for (int i = 0; i < 4; i++) {
                acc[i][0] = fmaf(a[i].x, b[0].x, acc[i][0]);
                acc[i][1] = fmaf(a[i].x, b[0].y, acc[i][1]);
                acc[i][2] = fmaf(a[i].x, b[0].z, acc[i][2]);
                acc[i][3] = fmaf(a[i].x, b[0].w, acc[i][3]);
                acc[i][0] = fmaf(a[i].y, b[1].x, acc[i][0]);
                acc[i][1] = fmaf(a[i].y, b[1].y, acc[i][1]);
                acc[i][2] = fmaf(a[i].y, b[1].z, acc[i][2]);
                acc[i][3] = fmaf(a[i].y, b[1].w, acc[i][3]);
                acc[i][0] = fmaf(a[i].z, b[2].x, acc[i][0]);
                acc[i][1] = fmaf(a[i].z, b[2].y, acc[i][1]);
                acc[i][2] = fmaf(a[i].z, b[2].z, acc[i][2]);
                acc[i][3] = fmaf(a[i].z, b[2].w, acc[i][3]);
                acc[i][0] = fmaf(a[i].w, b[3].x, acc[i][0]);
                acc[i][1] = fmaf(a[i].w, b[3].y, acc[i][1]);
                acc[i][2] = fmaf(a[i].w, b[3].z, acc[i][2]);
                acc[i][3] = fmaf(a[i].w, b[3].w, acc[i][3]);
            }
        }
    }

#pragma unroll
    for (int i = 0; i < 4; i++) {
        int gr = row0 + ty * 4 + i;
        if (gr < n) {
            float sc = dinv[gr];
            union { __half2 h[2]; unsigned long long u; } pk;
            pk.h[0] = __floats2half2_rn(acc[i][0] * sc, acc[i][1] * sc);
            pk.h[1] = __floats2half2_rn(acc[i][2] * sc, acc[i][3] * sc);
            *(unsigned long long*)(out + (size_t)gr * HID + tx * 4) = pk.u;
        }
    }
}

// ---------------- CSR gather aggregation (fused selfloop + bias + relu [+ logits]) ----
// fp16 rows: 64 feats = 128 B = ONE cache line per edge. One node per 32-lane
// half-wave; each lane owns 2 features (__half2). Output h written fp16.
// LOGITS: direct (non-atomic) logits write via 32-lane shfl reduce.

template<bool LOGITS>
__global__ void gather_k(const __half* __restrict__ tS, const int* __restrict__ rowptr,
                         const int* __restrict__ col, const float* __restrict__ dinv,
                         const float* __restrict__ b, __half* __restrict__ out,
                         const float* __restrict__ Wa, const float* __restrict__ ba,
                         float* __restrict__ logits, int n) {
    int node = (int)((blockIdx.x * (size_t)blockDim.x + threadIdx.x) >> 5);
    int lane = threadIdx.x & 31;
    if (node >= n) return;
    int beg = rowptr[node], end = rowptr[node + 1];
    const __half2* tl = (const __half2*)tS + lane;   // row stride = 32 half2
    float2 acc = __half22float2(tl[node * 32]);      // self-loop term
    int e = beg;
    for (; e + 16 <= end; e += 16) {
        int s[16];
        __half2 v[16];
#pragma unroll
        for (int j = 0; j < 16; j++) s[j] = col[e + j];
#pragma unroll
        for (int j = 0; j < 16; j++) v[j] = tl[s[j] * 32];
        float2 t0 = make_float2(0.f, 0.f), t1 = make_float2(0.f, 0.f);
#pragma unroll
        for (int j = 0; j < 8; j++) {
            float2 f = __half22float2(v[j]);
            t0.x += f.x; t0.y += f.y;
        }
#pragma unroll
        for (int j = 8; j < 16; j++) {
            float2 f = __half22float2(v[j]);
            t1.x += f.x; t1.y += f.y;
        }
        acc.x += t0.x + t1.x;
        acc.y += t0.y + t1.y;
    }
    for (; e + 4 <= end; e += 4) {
        __half2 v0 = tl[col[e] * 32];
        __half2 v1 = tl[col[e + 1] * 32];
        __half2 v2 = tl[col[e + 2] * 32];
        __half2 v3 = tl[col[e + 3] * 32];
        float2 f0 = __half22float2(v0), f1 = __half22float2(v1);
        float2 f2 = __half22float2(v2), f3 = __half22float2(v3);
        acc.x += (f0.x + f1.x) + (f2.x + f3.x);
        acc.y += (f0.y + f1.y) + (f2.y + f3.y);
    }
    for (; e < end; ++e) {
        float2 f = __half22float2(tl[col[e] * 32]);
        acc.x += f.x; acc.y += f.y;
    }
    float d = dinv[node];
    float2 bb = *(const float2*)(b + 2 * lane);
    float h0 = fmaxf(fmaf(d, acc.x, bb.x), 0.0f);
    float h1 = fmaxf(fmaf(d, acc.y, bb.y), 0.0f);
    ((__half2*)out)[node * 32 + lane] = __floats2half2_rn(h0, h1);
    if (LOGITS) {
        float2 wa = *(const float2*)(Wa + 2 * lane);
        float p = h0 * wa.x + h1 * wa.y;
#pragma unroll
        for (int off = 16; off > 0; off >>= 1) p += __shfl_down(p, off, 32);
        if (lane == 0) logits[node] = p + ba[0];
    }
}

// ---------------- mean-pool partials (fp16 h, run-length batched) ----------------

__global__ void pool_k(const __half* __restrict__ h, const int* __restrict__ batch,
                       float* __restrict__ pooled, int n) {
    int lane = threadIdx.x & 31;
    int grp  = threadIdx.x >> 5;                 // 8 groups of 32 lanes
    int start = (blockIdx.x * 8 + grp) * 64;
    if (start >= n) return;
    int end = min(start + 64, n);
    const __half2* hp = (const __half2*)h + lane;
    float2 acc = make_float2(0.f, 0.f);
    int curg = -1;
    for (int i = start; i < end; i++) {
        int g = batch[i];
        if (g != curg) {
            if (curg >= 0) {
                atomicAdd(&pooled[curg * HID + 2 * lane], acc.x);
                atomicAdd(&pooled[curg * HID + 2 * lane + 1], acc.y);
            }
            curg = g; acc = make_float2(0.f, 0.f);
        }
        float2 f = __half22float2(hp[i * 32]);
        acc.x += f.x; acc.y += f.y;
    }
    atomicAdd(&pooled[curg * HID + 2 * lane], acc.x);
    atomicAdd(&pooled[curg * HID + 2 * lane + 1], acc.y);
}

// ---------------- value head (counts via binary search on sorted batch) ----------------

__global__ void value_k(const float* __restrict__ pooled, const int* __restrict__ batch,
                        const float* __restrict__ Wc, const float* __restrict__ bc,
                        float* __restrict__ val, int n, int g) {
    int gw   = (int)((blockIdx.x * (size_t)blockDim.x + threadIdx.x) >> 6);
    int lane = threadIdx.x & 63;
    if (gw >= g) return;
    int lo = 0, hi = n;
    while (lo < hi) { int m = (lo + hi) >> 1; if (batch[m] < gw) lo = m + 1; else hi = m; }
    int b0 = lo;
    lo = 0; hi = n;
    while (lo < hi) { int m = (lo + hi) >> 1; if (batch[m] < gw + 1) lo = m + 1; else hi = m; }
    float cnt = fmaxf((float)(lo - b0), 1.0f);
    float p = (pooled[gw * HID + lane] / cnt) * Wc[lane];
#pragma unroll
    for (int off = 32; off > 0; off >>= 1) p += __shfl_down(p, off);
    if (lane == 0) val[gw] = p + bc[0];
}

extern "C" void kernel_launch(void* const* d_in, const int* in_sizes, int n_in,
                              void* d_out, int out_size, void* d_ws, size_t ws_size,
                              hipStream_t stream) {
    const float* x     = (const float*)d_in[0];
    const int*   ei    = (const int*)d_in[1];
    const int*   batch = (const int*)d_in[2];
    const float* W1    = (const float*)d_in[3];
    const float* b1    = (const float*)d_in[4];
    const float* W2    = (const float*)d_in[5];
    const float* b2    = (const float*)d_in[6];
    const float* Wa    = (const float*)d_in[7];
    const float* ba    = (const float*)d_in[8];
    const float* Wc    = (const float*)d_in[9];
    const float* bc    = (const float*)d_in[10];

    const int n = in_sizes[0] / FEAT;   // 100000
    const int e = in_sizes[1] / 2;      // 1600000
    const int g = out_size - n;         // 64
    const int* src = ei;
    const int* dst = ei + e;

    const int nb = (n + BNODES - 1) >> BSH;   // buckets (782)
    const int L  = nb * PB;                    // offset table length

    // workspace layout (packed aliases bufA: dead before first gemm)
    float*    ws     = (float*)d_ws;
    float*    dinv   = ws;                               // n
    float*    bufA   = dinv + n;                         // n*HID floats of space (tS fp16)
    float*    bufB   = bufA + (size_t)n * HID;           // n*HID floats of space (h fp16)
    float*    pooled = bufB + (size_t)n * HID;           // g*HID
    int*      table  = (int*)(pooled + (size_t)g * HID); // L
    int*      aux    = table + L;                        // 1024
    int*      rowptr = aux + 1024;                       // n+1
    int*      col    = rowptr + n + 1;                   // e
    unsigned* packed = (unsigned*)bufA;                  // e (aliased, transient)
    __half*   tS     = (__half*)bufA;                    // n*HID fp16 (after packed dead)
    __half*   h16    = (__half*)bufB;                    // n*HID fp16

    const int B = 256;
    const int gridT = (n + 63) / 64;
    const int gridG = (int)(((size_t)n * 32 + B - 1) / B);   // 32-lane group per node
    const int gridP = (n + 8 * 64 - 1) / (8 * 64);
    const int nb1   = (L + 1023) / 1024;

    hipMemsetAsync(pooled, 0, (size_t)g * HID * sizeof(float), stream);

    // two-level CSR build: bucket partition -> in-bucket counting sort
    part_hist_k<<<PB, B, 0, stream>>>(dst, table, e, nb);
    scan1_k<<<nb1, 1024, 0, stream>>>(table, aux, L);
    scan2_k<<<1, 1024, 0, stream>>>(aux, nb1);
    part_scatter_k<<<PB, B, 0, stream>>>(src, dst, table, aux, packed, e, nb);
    bucket_sort_k<<<nb, B, 0, stream>>>(packed, table, aux, col, rowptr, dinv, n, e, nb);

    // layer 1
    gemm_tile_k<FEAT, false><<<gridT, B, 0, stream>>>(x, W1, dinv, tS, n);
    gather_k<false><<<gridG, B, 0, stream>>>(tS, rowptr, col, dinv, b1, h16,
                                             nullptr, nullptr, nullptr, n);

    // layer 2 (logits fused into gather epilogue; h16 written for pool)
    gemm_tile_k<HID, true><<<gridT, B, 0, stream>>>(h16, W2, dinv, tS, n);
    gather_k<true><<<gridG, B, 0, stream>>>(tS, rowptr, col, dinv, b2, h16,
                                            Wa, ba, (float*)d_out, n);

    // heads
    pool_k<<<gridP, B, 0, stream>>>(h16, batch, pooled, n);
    value_k<<<(g * 64 + B - 1) / B, B, 0, stream>>>(pooled, batch, Wc, bc,
                                                    (float*)d_out + n, n, g);
}

// Round 6
// 304.791 us; speedup vs baseline: 1.1665x; 1.0587x over previous
//
#include <hip/hip_runtime.h>
#include <hip/hip_fp16.h>
#include <math.h>

#define FEAT 128
#define HID  64
#define BSH  7                 // 128 dst-nodes per bucket
#define BNODES (1 << BSH)
#define PB   256               // partition blocks (256: full-chip parallelism)
#define SRCM ((1u << 25) - 1)  // src in low 25 bits, dst_local in high 7
#define PSPLIT 16              // pool splits per group

// ---------------- stage 1: edge partition by dst-bucket ----------------

__global__ void part_hist_k(const int* __restrict__ dst, int* __restrict__ table,
                            int e, int nb) {
    __shared__ int lcnt[1024];
    for (int i = threadIdx.x; i < nb; i += 256) lcnt[i] = 0;
    __syncthreads();
    int eb = (e + PB - 1) / PB;
    int lo = blockIdx.x * eb, hi = min(lo + eb, e);
    for (int i = lo + threadIdx.x; i < hi; i += 256)
        atomicAdd(&lcnt[dst[i] >> BSH], 1);
    __syncthreads();
    for (int k = threadIdx.x; k < nb; k += 256)
        table[k * PB + blockIdx.x] = lcnt[k];
}

__global__ void scan1_k(int* __restrict__ data, int* __restrict__ aux, int L) {
    __shared__ int s[1024];
    int gid = blockIdx.x * 1024 + threadIdx.x;
    int v = (gid < L) ? data[gid] : 0;
    s[threadIdx.x] = v;
    __syncthreads();
    for (int off = 1; off < 1024; off <<= 1) {
        int t = (threadIdx.x >= off) ? s[threadIdx.x - off] : 0;
        __syncthreads();
        s[threadIdx.x] += t;
        __syncthreads();
    }
    if (gid < L) data[gid] = s[threadIdx.x] - v;            // exclusive in block
    if (threadIdx.x == 1023) aux[blockIdx.x] = s[1023];     // block total
}

__global__ void scan2_k(int* aux, int naux) {
    __shared__ int s[1024];
    int v = (threadIdx.x < naux) ? aux[threadIdx.x] : 0;
    s[threadIdx.x] = v;
    __syncthreads();
    for (int off = 1; off < 1024; off <<= 1) {
        int t = (threadIdx.x >= off) ? s[threadIdx.x - off] : 0;
        __syncthreads();
        s[threadIdx.x] += t;
        __syncthreads();
    }
    if (threadIdx.x < naux) aux[threadIdx.x] = s[threadIdx.x] - v;
}

__global__ void part_scatter_k(const int* __restrict__ src, const int* __restrict__ dst,
                               const int* __restrict__ table, const int* __restrict__ aux,
                               unsigned* __restrict__ packed, int e, int nb) {
    __shared__ int loff[1024];
    for (int k = threadIdx.x; k < nb; k += 256) {
        int idx = k * PB + blockIdx.x;
        loff[k] = table[idx] + aux[idx >> 10];
    }
    __syncthreads();
    int eb = (e + PB - 1) / PB;
    int lo = blockIdx.x * eb, hi = min(lo + eb, e);
    for (int i = lo + threadIdx.x; i < hi; i += 256) {
        int d = dst[i];
        int p = atomicAdd(&loff[d >> BSH], 1);
        packed[p] = ((unsigned)(d & (BNODES - 1)) << 25) | (unsigned)src[i];
    }
}

// ---------------- stage 2: per-bucket counting sort -> per-node CSR + dinv ----

__global__ void bucket_sort_k(const unsigned* __restrict__ packed,
                              const int* __restrict__ table, const int* __restrict__ aux,
                              int* __restrict__ col, int* __restrict__ rowptr,
                              float* __restrict__ dinv, int n, int e, int nb) {
    __shared__ int cnt[BNODES];
    __shared__ int s[BNODES];
    __shared__ int cur[BNODES];
    const int k = blockIdx.x;
    const int t = threadIdx.x;
    if (t < BNODES) cnt[t] = 0;
    __syncthreads();
    int i0 = k * PB;
    int i1 = (k + 1) * PB;
    const int bs = table[i0] + aux[i0 >> 10];
    const int be = (k + 1 < nb) ? (table[i1] + aux[i1 >> 10]) : e;
    for (int i = bs + t; i < be; i += 256)
        atomicAdd(&cnt[packed[i] >> 25], 1);
    __syncthreads();
    if (t < BNODES) s[t] = cnt[t];
    __syncthreads();
    for (int off = 1; off < BNODES; off <<= 1) {
        int v = (t < BNODES && t >= off) ? s[t - off] : 0;
        __syncthreads();
        if (t < BNODES) s[t] += v;
        __syncthreads();
    }
    if (t < BNODES) {
        int base = bs + s[t] - cnt[t];
        cur[t] = base;
        int node = (k << BSH) + t;
        if (node < n) {
            rowptr[node] = base;
            dinv[node] = 1.0f / sqrtf(1.0f + (float)cnt[t]);
            if (node == n - 1) rowptr[n] = base + cnt[t];
        }
    }
    __syncthreads();
    for (int i = bs + t; i < be; i += 256) {
        unsigned u = packed[i];
        int p = atomicAdd(&cur[u >> 25], 1);
        col[p] = (int)(u & SRCM);
    }
}

// ---------------- dense transform: out[n,64] = fp16((X[n,128] @ W1) * dinv[row]) ----

__global__ __launch_bounds__(256, 3)
void gemm_tile_k(const float* __restrict__ X, const float* __restrict__ W,
                 const float* __restrict__ dinv, __half* __restrict__ out, int n) {
    constexpr int K = FEAT;
    __shared__ float sX[64][K + 4];
    __shared__ float sW[64][64];       // one 64-row slab of W
    const int row0 = blockIdx.x * 64;
    const int t  = threadIdx.x;
    const int tx = t & 15;
    const int ty = t >> 4;

    const float* xb = X + (size_t)row0 * K;
#pragma unroll
    for (int it = 0; it < K / 16; ++it) {
        int fl = it * 1024 + t * 4;
        int r  = fl >> 7;
        int k  = fl & (K - 1);
        float4 v = make_float4(0.f, 0.f, 0.f, 0.f);
        if (row0 + r < n) v = *(const float4*)(xb + fl);
        *(float4*)&sX[r][k] = v;
    }

    float acc[4][4] = {};
#pragma unroll
    for (int ph = 0; ph < K / 64; ++ph) {
        __syncthreads();
#pragma unroll
        for (int it = 0; it < 4; ++it) {
            int fl = it * 1024 + t * 4;
            *(float4*)&sW[fl >> 6][fl & 63] = *(const float4*)(W + ph * 64 * HID + fl);
        }
        __syncthreads();

#pragma unroll 8
        for (int k = 0; k < 64; k += 4) {
            float4 a[4], b[4];
#pragma unroll
            for (int i = 0; i < 4; i++) a[i] = *(float4*)&sX[ty * 4 + i][ph * 64 + k];
#pragma unroll
            for (int j = 0; j < 4; j++) b[j] = *(float4*)&sW[k + j][tx * 4];
#pragma unroll
            for (int i = 0; i < 4; i++) {
                acc[i][0] = fmaf(a[i].x, b[0].x, acc[i][0]);
                acc[i][1] = fmaf(a[i].x, b[0].y, acc[i][1]);
                acc[i][2] = fmaf(a[i].x, b[0].z, acc[i][2]);
                acc[i][3] = fmaf(a[i].x, b[0].w, acc[i][3]);
                acc[i][0] = fmaf(a[i].y, b[1].x, acc[i][0]);
                acc[i][1] = fmaf(a[i].y, b[1].y, acc[i][1]);
                acc[i][2] = fmaf(a[i].y, b[1].z, acc[i][2]);
                acc[i][3] = fmaf(a[i].y, b[1].w, acc[i][3]);
                acc[i][0] = fmaf(a[i].z, b[2].x, acc[i][0]);
                acc[i][1] = fmaf(a[i].z, b[2].y, acc[i][1]);
                acc[i][2] = fmaf(a[i].z, b[2].z, acc[i][2]);
                acc[i][3] = fmaf(a[i].z, b[2].w, acc[i][3]);
                acc[i][0] = fmaf(a[i].w, b[3].x, acc[i][0]);
                acc[i][1] = fmaf(a[i].w, b[3].y, acc[i][1]);
                acc[i][2] = fmaf(a[i].w, b[3].z, acc[i][2]);
                acc[i][3] = fmaf(a[i].w, b[3].w, acc[i][3]);
            }
        }
    }

#pragma unroll
    for (int i = 0; i < 4; i++) {
        int gr = row0 + ty * 4 + i;
        if (gr < n) {
            float sc = dinv[gr];
            union { __half2 h[2]; unsigned long long u; } pk;
            pk.h[0] = __floats2half2_rn(acc[i][0] * sc, acc[i][1] * sc);
            pk.h[1] = __floats2half2_rn(acc[i][2] * sc, acc[i][3] * sc);
            *(unsigned long long*)(out + (size_t)gr * HID + tx * 4) = pk.u;
        }
    }
}

// ---------------- layer-1 gather + FUSED h@W2*dinv epilogue ----------------
// Gather as before (fp16 rows, 32 lanes/node). After relu, the half-wave holds
// the full h[64] (2/lane, fp32). W2 staged once per block in LDS as packed
// fp16 pairs (8KB); h broadcast via shfl of a packed half2. Output = next
// layer's transformed+scaled tS2 (fp16) — deletes the gemm<64> kernel.

__global__ void gather1_k(const __half* __restrict__ tS, const int* __restrict__ rowptr,
                          const int* __restrict__ col, const float* __restrict__ dinv,
                          const float* __restrict__ b, const float* __restrict__ W2,
                          __half* __restrict__ out, int n) {
    __shared__ __half2 sW2[32][32][2];   // [kk][j]: rows 2kk,2kk+1, cols 2j,2j+1
    for (int i = threadIdx.x; i < 32 * 32; i += 256) {
        int kk = i >> 5, j = i & 31;
        float2 a = *(const float2*)(W2 + (2 * kk) * HID + 2 * j);
        float2 c = *(const float2*)(W2 + (2 * kk + 1) * HID + 2 * j);
        sW2[kk][j][0] = __floats2half2_rn(a.x, a.y);
        sW2[kk][j][1] = __floats2half2_rn(c.x, c.y);
    }
    __syncthreads();

    int node = (int)((blockIdx.x * (size_t)blockDim.x + threadIdx.x) >> 5);
    int lane = threadIdx.x & 31;
    if (node >= n) return;
    int beg = rowptr[node], end = rowptr[node + 1];
    const __half2* tl = (const __half2*)tS + lane;   // row stride = 32 half2
    float2 acc = __half22float2(tl[node * 32]);      // self-loop term
    int e = beg;
    for (; e + 16 <= end; e += 16) {
        int s[16];
        __half2 v[16];
#pragma unroll
        for (int j = 0; j < 16; j++) s[j] = col[e + j];
#pragma unroll
        for (int j = 0; j < 16; j++) v[j] = tl[s[j] * 32];
        float2 t0 = make_float2(0.f, 0.f), t1 = make_float2(0.f, 0.f);
#pragma unroll
        for (int j = 0; j < 8; j++) {
            float2 f = __half22float2(v[j]);
            t0.x += f.x; t0.y += f.y;
        }
#pragma unroll
        for (int j = 8; j < 16; j++) {
            float2 f = __half22float2(v[j]);
            t1.x += f.x; t1.y += f.y;
        }
        acc.x += t0.x + t1.x;
        acc.y += t0.y + t1.y;
    }
    for (; e + 4 <= end; e += 4) {
        __half2 v0 = tl[col[e] * 32];
        __half2 v1 = tl[col[e + 1] * 32];
        __half2 v2 = tl[col[e + 2] * 32];
        __half2 v3 = tl[col[e + 3] * 32];
        float2 f0 = __half22float2(v0), f1 = __half22float2(v1);
        float2 f2 = __half22float2(v2), f3 = __half22float2(v3);
        acc.x += (f0.x + f1.x) + (f2.x + f3.x);
        acc.y += (f0.y + f1.y) + (f2.y + f3.y);
    }
    for (; e < end; ++e) {
        float2 f = __half22float2(tl[col[e] * 32]);
        acc.x += f.x; acc.y += f.y;
    }
    float d = dinv[node];
    float2 bb = *(const float2*)(b + 2 * lane);
    float h0 = fmaxf(fmaf(d, acc.x, bb.x), 0.0f);
    float h1 = fmaxf(fmaf(d, acc.y, bb.y), 0.0f);

    // fused: tS2[node] = (h @ W2) * dinv   (h quantized to fp16, same as before)
    __half2 hh = __floats2half2_rn(h0, h1);
    int hu = *(int*)&hh;
    float2 o = make_float2(0.f, 0.f);
#pragma unroll
    for (int kk = 0; kk < 32; ++kk) {
        int pu = __shfl(hu, kk, 32);
        __half2 hv = *(__half2*)&pu;
        float2 hf = __half22float2(hv);       // h[2kk], h[2kk+1]
        float2 w0 = __half22float2(sW2[kk][lane][0]);
        float2 w1 = __half22float2(sW2[kk][lane][1]);
        o.x = fmaf(hf.x, w0.x, o.x); o.y = fmaf(hf.x, w0.y, o.y);
        o.x = fmaf(hf.y, w1.x, o.x); o.y = fmaf(hf.y, w1.y, o.y);
    }
    ((__half2*)out)[node * 32 + lane] = __floats2half2_rn(o.x * d, o.y * d);
}

// ---------------- layer-2 gather (logits fused; h written fp16 for pool) ----

__global__ void gather2_k(const __half* __restrict__ tS, const int* __restrict__ rowptr,
                          const int* __restrict__ col, const float* __restrict__ dinv,
                          const float* __restrict__ b, __half* __restrict__ out,
                          const float* __restrict__ Wa, const float* __restrict__ ba,
                          float* __restrict__ logits, int n) {
    int node = (int)((blockIdx.x * (size_t)blockDim.x + threadIdx.x) >> 5);
    int lane = threadIdx.x & 31;
    if (node >= n) return;
    int beg = rowptr[node], end = rowptr[node + 1];
    const __half2* tl = (const __half2*)tS + lane;
    float2 acc = __half22float2(tl[node * 32]);
    int e = beg;
    for (; e + 16 <= end; e += 16) {
        int s[16];
        __half2 v[16];
#pragma unroll
        for (int j = 0; j < 16; j++) s[j] = col[e + j];
#pragma unroll
        for (int j = 0; j < 16; j++) v[j] = tl[s[j] * 32];
        float2 t0 = make_float2(0.f, 0.f), t1 = make_float2(0.f, 0.f);
#pragma unroll
        for (int j = 0; j < 8; j++) {
            float2 f = __half22float2(v[j]);
            t0.x += f.x; t0.y += f.y;
        }
#pragma unroll
        for (int j = 8; j < 16; j++) {
            float2 f = __half22float2(v[j]);
            t1.x += f.x; t1.y += f.y;
        }
        acc.x += t0.x + t1.x;
        acc.y += t0.y + t1.y;
    }
    for (; e + 4 <= end; e += 4) {
        __half2 v0 = tl[col[e] * 32];
        __half2 v1 = tl[col[e + 1] * 32];
        __half2 v2 = tl[col[e + 2] * 32];
        __half2 v3 = tl[col[e + 3] * 32];
        float2 f0 = __half22float2(v0), f1 = __half22float2(v1);
        float2 f2 = __half22float2(v2), f3 = __half22float2(v3);
        acc.x += (f0.x + f1.x) + (f2.x + f3.x);
        acc.y += (f0.y + f1.y) + (f2.y + f3.y);
    }
    for (; e < end; ++e) {
        float2 f = __half22float2(tl[col[e] * 32]);
        acc.x += f.x; acc.y += f.y;
    }
    float d = dinv[node];
    float2 bb = *(const float2*)(b + 2 * lane);
    float h0 = fmaxf(fmaf(d, acc.x, bb.x), 0.0f);
    float h1 = fmaxf(fmaf(d, acc.y, bb.y), 0.0f);
    ((__half2*)out)[node * 32 + lane] = __floats2half2_rn(h0, h1);
    float2 wa = *(const float2*)(Wa + 2 * lane);
    float p = h0 * wa.x + h1 * wa.y;
#pragma unroll
    for (int off = 16; off > 0; off >>= 1) p += __shfl_down(p, off, 32);
    if (lane == 0) logits[node] = p + ba[0];
}

// ---------------- parallel mean-pool: 64 groups x 16 splits, branch-free ----

__global__ void pool2_k(const __half* __restrict__ h, const int* __restrict__ batch,
                        float* __restrict__ pooled, int n) {
    const int gid  = blockIdx.x / PSPLIT;
    const int part = blockIdx.x % PSPLIT;
    // group bounds via binary search on sorted batch (scalar, cached)
    int lo = 0, hi = n;
    while (lo < hi) { int m = (lo + hi) >> 1; if (batch[m] < gid) lo = m + 1; else hi = m; }
    const int b0 = lo;
    hi = n;
    while (lo < hi) { int m = (lo + hi) >> 1; if (batch[m] < gid + 1) lo = m + 1; else hi = m; }
    const int b1 = lo;
    const int chunk = (b1 - b0 + PSPLIT - 1) / PSPLIT;
    const int r0 = b0 + part * chunk;
    const int r1 = min(r0 + chunk, b1);
    const int lane = threadIdx.x & 31;
    const int rg   = threadIdx.x >> 5;       // 8 rows in flight
    const __half2* hp = (const __half2*)h + lane;
    float2 acc = make_float2(0.f, 0.f);
    for (int i = r0 + rg; i < r1; i += 8) {
        float2 f = __half22float2(hp[(size_t)i * 32]);
        acc.x += f.x; acc.y += f.y;
    }
    __shared__ float2 red[8][32];
    red[rg][lane] = acc;
    __syncthreads();
    if (threadIdx.x < 32) {
        float2 s = make_float2(0.f, 0.f);
#pragma unroll
        for (int r = 0; r < 8; r++) { s.x += red[r][threadIdx.x].x; s.y += red[r][threadIdx.x].y; }
        atomicAdd(&pooled[gid * HID + 2 * threadIdx.x], s.x);
        atomicAdd(&pooled[gid * HID + 2 * threadIdx.x + 1], s.y);
    }
}

// ---------------- value head (counts via binary search on sorted batch) ----------------

__global__ void value_k(const float* __restrict__ pooled, const int* __restrict__ batch,
                        const float* __restrict__ Wc, const float* __restrict__ bc,
                        float* __restrict__ val, int n, int g) {
    int gw   = (int)((blockIdx.x * (size_t)blockDim.x + threadIdx.x) >> 6);
    int lane = threadIdx.x & 63;
    if (gw >= g) return;
    int lo = 0, hi = n;
    while (lo < hi) { int m = (lo + hi) >> 1; if (batch[m] < gw) lo = m + 1; else hi = m; }
    int b0 = lo;
    lo = 0; hi = n;
    while (lo < hi) { int m = (lo + hi) >> 1; if (batch[m] < gw + 1) lo = m + 1; else hi = m; }
    float cnt = fmaxf((float)(lo - b0), 1.0f);
    float p = (pooled[gw * HID + lane] / cnt) * Wc[lane];
#pragma unroll
    for (int off = 32; off > 0; off >>= 1) p += __shfl_down(p, off);
    if (lane == 0) val[gw] = p + bc[0];
}

extern "C" void kernel_launch(void* const* d_in, const int* in_sizes, int n_in,
                              void* d_out, int out_size, void* d_ws, size_t ws_size,
                              hipStream_t stream) {
    const float* x     = (const float*)d_in[0];
    const int*   ei    = (const int*)d_in[1];
    const int*   batch = (const int*)d_in[2];
    const float* W1    = (const float*)d_in[3];
    const float* b1    = (const float*)d_in[4];
    const float* W2    = (const float*)d_in[5];
    const float* b2    = (const float*)d_in[6];
    const float* Wa    = (const float*)d_in[7];
    const float* ba    = (const float*)d_in[8];
    const float* Wc    = (const float*)d_in[9];
    const float* bc    = (const float*)d_in[10];

    const int n = in_sizes[0] / FEAT;   // 100000
    const int e = in_sizes[1] / 2;      // 1600000
    const int g = out_size - n;         // 64
    const int* src = ei;
    const int* dst = ei + e;

    const int nb = (n + BNODES - 1) >> BSH;   // buckets (782)
    const int L  = nb * PB;                    // offset table length

    // workspace layout (packed aliases bufA: dead before first gemm)
    float*    ws     = (float*)d_ws;
    float*    dinv   = ws;                               // n
    float*    bufA   = dinv + n;                         // n*HID floats (tS1 fp16 / h2 fp16)
    float*    bufB   = bufA + (size_t)n * HID;           // n*HID floats (tS2 fp16)
    float*    pooled = bufB + (size_t)n * HID;           // g*HID
    int*      table  = (int*)(pooled + (size_t)g * HID); // L
    int*      aux    = table + L;                        // 1024
    int*      rowptr = aux + 1024;                       // n+1
    int*      col    = rowptr + n + 1;                   // e
    unsigned* packed = (unsigned*)bufA;                  // e (aliased, transient)
    __half*   tS1    = (__half*)bufA;                    // layer-1 transformed (after packed dead)
    __half*   tS2    = (__half*)bufB;                    // layer-2 transformed (gather1 output)
    __half*   h2     = (__half*)bufA;                    // layer-2 h (gather2 output, overwrites tS1)

    const int B = 256;
    const int gridT = (n + 63) / 64;
    const int gridG = (int)(((size_t)n * 32 + B - 1) / B);   // 32-lane group per node
    const int nb1   = (L + 1023) / 1024;

    (void)hipMemsetAsync(pooled, 0, (size_t)g * HID * sizeof(float), stream);

    // two-level CSR build: bucket partition -> in-bucket counting sort
    part_hist_k<<<PB, B, 0, stream>>>(dst, table, e, nb);
    scan1_k<<<nb1, 1024, 0, stream>>>(table, aux, L);
    scan2_k<<<1, 1024, 0, stream>>>(aux, nb1);
    part_scatter_k<<<PB, B, 0, stream>>>(src, dst, table, aux, packed, e, nb);
    bucket_sort_k<<<nb, B, 0, stream>>>(packed, table, aux, col, rowptr, dinv, n, e, nb);

    // layer 1 transform + gather (gather fuses h@W2*dinv -> tS2; gemm64 deleted)
    gemm_tile_k<<<gridT, B, 0, stream>>>(x, W1, dinv, tS1, n);
    gather1_k<<<gridG, B, 0, stream>>>(tS1, rowptr, col, dinv, b1, W2, tS2, n);

    // layer 2 gather (logits fused; h2 written for pool)
    gather2_k<<<gridG, B, 0, stream>>>(tS2, rowptr, col, dinv, b2, h2,
                                       Wa, ba, (float*)d_out, n);

    // heads
    pool2_k<<<g * PSPLIT, B, 0, stream>>>(h2, batch, pooled, n);
    value_k<<<(g * 64 + B - 1) / B, B, 0, stream>>>(pooled, batch, Wc, bc,
                                                    (float*)d_out + n, n, g);
}

// Round 7
// 303.379 us; speedup vs baseline: 1.1720x; 1.0047x over previous
//
#include <hip/hip_runtime.h>
#include <hip/hip_fp16.h>
#include <math.h>

#define FEAT 128
#define HID  64
#define BSH  7                 // 128 dst-nodes per bucket
#define BNODES (1 << BSH)
#define PB   256               // partition blocks (256: full-chip parallelism)
#define SRCM ((1u << 25) - 1)  // src in low 25 bits, dst_local in high 7
#define PSPLIT 16              // pool splits per group

typedef _Float16 h2v __attribute__((ext_vector_type(2)));

// ---------------- stage 1: edge partition by dst-bucket ----------------

__global__ void part_hist_k(const int* __restrict__ dst, int* __restrict__ table,
                            int e, int nb) {
    __shared__ int lcnt[1024];
    for (int i = threadIdx.x; i < nb; i += 256) lcnt[i] = 0;
    __syncthreads();
    int eb = (e + PB - 1) / PB;
    int lo = blockIdx.x * eb, hi = min(lo + eb, e);
    for (int i = lo + threadIdx.x; i < hi; i += 256)
        atomicAdd(&lcnt[dst[i] >> BSH], 1);
    __syncthreads();
    for (int k = threadIdx.x; k < nb; k += 256)
        table[k * PB + blockIdx.x] = lcnt[k];
}

__global__ void scan1_k(int* __restrict__ data, int* __restrict__ aux, int L) {
    __shared__ int s[1024];
    int gid = blockIdx.x * 1024 + threadIdx.x;
    int v = (gid < L) ? data[gid] : 0;
    s[threadIdx.x] = v;
    __syncthreads();
    for (int off = 1; off < 1024; off <<= 1) {
        int t = (threadIdx.x >= off) ? s[threadIdx.x - off] : 0;
        __syncthreads();
        s[threadIdx.x] += t;
        __syncthreads();
    }
    if (gid < L) data[gid] = s[threadIdx.x] - v;            // exclusive in block
    if (threadIdx.x == 1023) aux[blockIdx.x] = s[1023];     // block total
}

__global__ void scan2_k(int* aux, int naux) {
    __shared__ int s[1024];
    int v = (threadIdx.x < naux) ? aux[threadIdx.x] : 0;
    s[threadIdx.x] = v;
    __syncthreads();
    for (int off = 1; off < 1024; off <<= 1) {
        int t = (threadIdx.x >= off) ? s[threadIdx.x - off] : 0;
        __syncthreads();
        s[threadIdx.x] += t;
        __syncthreads();
    }
    if (threadIdx.x < naux) aux[threadIdx.x] = s[threadIdx.x] - v;
}

__global__ void part_scatter_k(const int* __restrict__ src, const int* __restrict__ dst,
                               const int* __restrict__ table, const int* __restrict__ aux,
                               unsigned* __restrict__ packed, int e, int nb) {
    __shared__ int loff[1024];
    for (int k = threadIdx.x; k < nb; k += 256) {
        int idx = k * PB + blockIdx.x;
        loff[k] = table[idx] + aux[idx >> 10];
    }
    __syncthreads();
    int eb = (e + PB - 1) / PB;
    int lo = blockIdx.x * eb, hi = min(lo + eb, e);
    for (int i = lo + threadIdx.x; i < hi; i += 256) {
        int d = dst[i];
        int p = atomicAdd(&loff[d >> BSH], 1);
        packed[p] = ((unsigned)(d & (BNODES - 1)) << 25) | (unsigned)src[i];
    }
}

// ---------------- stage 2: per-bucket counting sort -> per-node CSR + dinv ----

__global__ void bucket_sort_k(const unsigned* __restrict__ packed,
                              const int* __restrict__ table, const int* __restrict__ aux,
                              int* __restrict__ col, int* __restrict__ rowptr,
                              float* __restrict__ dinv, int n, int e, int nb) {
    __shared__ int cnt[BNODES];
    __shared__ int s[BNODES];
    __shared__ int cur[BNODES];
    const int k = blockIdx.x;
    const int t = threadIdx.x;
    if (t < BNODES) cnt[t] = 0;
    __syncthreads();
    int i0 = k * PB;
    int i1 = (k + 1) * PB;
    const int bs = table[i0] + aux[i0 >> 10];
    const int be = (k + 1 < nb) ? (table[i1] + aux[i1 >> 10]) : e;
    for (int i = bs + t; i < be; i += 256)
        atomicAdd(&cnt[packed[i] >> 25], 1);
    __syncthreads();
    if (t < BNODES) s[t] = cnt[t];
    __syncthreads();
    for (int off = 1; off < BNODES; off <<= 1) {
        int v = (t < BNODES && t >= off) ? s[t - off] : 0;
        __syncthreads();
        if (t < BNODES) s[t] += v;
        __syncthreads();
    }
    if (t < BNODES) {
        int base = bs + s[t] - cnt[t];
        cur[t] = base;
        int node = (k << BSH) + t;
        if (node < n) {
            rowptr[node] = base;
            dinv[node] = 1.0f / sqrtf(1.0f + (float)cnt[t]);
            if (node == n - 1) rowptr[n] = base + cnt[t];
        }
    }
    __syncthreads();
    for (int i = bs + t; i < be; i += 256) {
        unsigned u = packed[i];
        int p = atomicAdd(&cur[u >> 25], 1);
        col[p] = (int)(u & SRCM);
    }
}

// ---------------- dense transform: out[n,64] = fp16((X[n,128] @ W1) * dinv[row]) ----

__global__ __launch_bounds__(256, 3)
void gemm_tile_k(const float* __restrict__ X, const float* __restrict__ W,
                 const float* __restrict__ dinv, __half* __restrict__ out, int n) {
    constexpr int K = FEAT;
    __shared__ float sX[64][K + 4];
    __shared__ float sW[64][64];       // one 64-row slab of W
    const int row0 = blockIdx.x * 64;
    const int t  = threadIdx.x;
    const int tx = t & 15;
    const int ty = t >> 4;

    const float* xb = X + (size_t)row0 * K;
#pragma unroll
    for (int it = 0; it < K / 16; ++it) {
        int fl = it * 1024 + t * 4;
        int r  = fl >> 7;
        int k  = fl & (K - 1);
        float4 v = make_float4(0.f, 0.f, 0.f, 0.f);
        if (row0 + r < n) v = *(const float4*)(xb + fl);
        *(float4*)&sX[r][k] = v;
    }

    float acc[4][4] = {};
#pragma unroll
    for (int ph = 0; ph < K / 64; ++ph) {
        __syncthreads();
#pragma unroll
        for (int it = 0; it < 4; ++it) {
            int fl = it * 1024 + t * 4;
            *(float4*)&sW[fl >> 6][fl & 63] = *(const float4*)(W + ph * 64 * HID + fl);
        }
        __syncthreads();

#pragma unroll 8
        for (int k = 0; k < 64; k += 4) {
            float4 a[4], b[4];
#pragma unroll
            for (int i = 0; i < 4; i++) a[i] = *(float4*)&sX[ty * 4 + i][ph * 64 + k];
#pragma unroll
            for (int j = 0; j < 4; j++) b[j] = *(float4*)&sW[k + j][tx * 4];
#pragma unroll
            for (int i = 0; i < 4; i++) {
                acc[i][0] = fmaf(a[i].x, b[0].x, acc[i][0]);
                acc[i][1] = fmaf(a[i].x, b[0].y, acc[i][1]);
                acc[i][2] = fmaf(a[i].x, b[0].z, acc[i][2]);
                acc[i][3] = fmaf(a[i].x, b[0].w, acc[i][3]);
                acc[i][0] = fmaf(a[i].y, b[1].x, acc[i][0]);
                acc[i][1] = fmaf(a[i].y, b[1].y, acc[i][1]);
                acc[i][2] = fmaf(a[i].y, b[1].z, acc[i][2]);
                acc[i][3] = fmaf(a[i].y, b[1].w, acc[i][3]);
                acc[i][0] = fmaf(a[i].z, b[2].x, acc[i][0]);
                acc[i][1] = fmaf(a[i].z, b[2].y, acc[i][1]);
                acc[i][2] = fmaf(a[i].z, b[2].z, acc[i][2]);
                acc[i][3] = fmaf(a[i].z, b[2].w, acc[i][3]);
                acc[i][0] = fmaf(a[i].w, b[3].x, acc[i][0]);
                acc[i][1] = fmaf(a[i].w, b[3].y, acc[i][1]);
                acc[i][2] = fmaf(a[i].w, b[3].z, acc[i][2]);
                acc[i][3] = fmaf(a[i].w, b[3].w, acc[i][3]);
            }
        }
    }

#pragma unroll
    for (int i = 0; i < 4; i++) {
        int gr = row0 + ty * 4 + i;
        if (gr < n) {
            float sc = dinv[gr];
            union { __half2 h[2]; unsigned long long u; } pk;
            pk.h[0] = __floats2half2_rn(acc[i][0] * sc, acc[i][1] * sc);
            pk.h[1] = __floats2half2_rn(acc[i][2] * sc, acc[i][3] * sc);
            *(unsigned long long*)(out + (size_t)gr * HID + tx * 4) = pk.u;
        }
    }
}

// ---------------- layer-1 gather + FUSED h@W2*dinv epilogue (fdot2) ----------------
// Gather: fp16 rows, 32 lanes/node. Epilogue: W2 staged row-pair-packed —
// sW2p[kk][c] = {W2[2kk][c], W2[2kk+1][c]} — so each kk step is 1 shfl +
// 1 ds_read_b64 + 2 v_dot2_f32_f16 (fp32 accumulate; numerics identical to
// the cvt+fma version, ~2.5x fewer VALU ops).

__global__ void gather1_k(const __half* __restrict__ tS, const int* __restrict__ rowptr,
                          const int* __restrict__ col, const float* __restrict__ dinv,
                          const float* __restrict__ b, const float* __restrict__ W2,
                          __half* __restrict__ out, int n) {
    __shared__ __half2 sW2p[32][64];   // [kk][c] = (W2[2kk][c], W2[2kk+1][c])
    for (int i = threadIdx.x; i < 32 * 64; i += 256) {
        int kk = i >> 6, c = i & 63;
        float a = W2[(2 * kk) * HID + c];
        float d2 = W2[(2 * kk + 1) * HID + c];
        sW2p[kk][c] = __floats2half2_rn(a, d2);
    }
    __syncthreads();

    int node = (int)((blockIdx.x * (size_t)blockDim.x + threadIdx.x) >> 5);
    int lane = threadIdx.x & 31;
    if (node >= n) return;
    int beg = rowptr[node], end = rowptr[node + 1];
    const __half2* tl = (const __half2*)tS + lane;   // row stride = 32 half2
    float2 acc = __half22float2(tl[node * 32]);      // self-loop term
    int e = beg;
    for (; e + 16 <= end; e += 16) {
        int s[16];
        __half2 v[16];
#pragma unroll
        for (int j = 0; j < 16; j++) s[j] = col[e + j];
#pragma unroll
        for (int j = 0; j < 16; j++) v[j] = tl[s[j] * 32];
        float2 t0 = make_float2(0.f, 0.f), t1 = make_float2(0.f, 0.f);
#pragma unroll
        for (int j = 0; j < 8; j++) {
            float2 f = __half22float2(v[j]);
            t0.x += f.x; t0.y += f.y;
        }
#pragma unroll
        for (int j = 8; j < 16; j++) {
            float2 f = __half22float2(v[j]);
            t1.x += f.x; t1.y += f.y;
        }
        acc.x += t0.x + t1.x;
        acc.y += t0.y + t1.y;
    }
    for (; e + 4 <= end; e += 4) {
        __half2 v0 = tl[col[e] * 32];
        __half2 v1 = tl[col[e + 1] * 32];
        __half2 v2 = tl[col[e + 2] * 32];
        __half2 v3 = tl[col[e + 3] * 32];
        float2 f0 = __half22float2(v0), f1 = __half22float2(v1);
        float2 f2 = __half22float2(v2), f3 = __half22float2(v3);
        acc.x += (f0.x + f1.x) + (f2.x + f3.x);
        acc.y += (f0.y + f1.y) + (f2.y + f3.y);
    }
    for (; e < end; ++e) {
        float2 f = __half22float2(tl[col[e] * 32]);
        acc.x += f.x; acc.y += f.y;
    }
    float d = dinv[node];
    float2 bb = *(const float2*)(b + 2 * lane);
    float h0 = fmaxf(fmaf(d, acc.x, bb.x), 0.0f);
    float h1 = fmaxf(fmaf(d, acc.y, bb.y), 0.0f);

    // fused: tS2[node] = (h @ W2) * dinv   (h quantized to fp16, same as before)
    __half2 hh = __floats2half2_rn(h0, h1);
    int hu = *(int*)&hh;
    float o0 = 0.f, o1 = 0.f;
#if __has_builtin(__builtin_amdgcn_fdot2)
    const uint2* wrow = (const uint2*)&sW2p[0][2 * lane];   // 8B: cols 2lane,2lane+1
#pragma unroll
    for (int kk = 0; kk < 32; ++kk) {
        int pu = __shfl(hu, kk, 32);
        union { int i; h2v v; } hp; hp.i = pu;
        union { uint2 u; struct { unsigned a, b; } s; } w;
        w.u = *(const uint2*)((const char*)wrow + kk * (64 * 4));
        union { unsigned u; h2v v; } w0, w1;
        w0.u = w.s.a; w1.u = w.s.b;
        o0 = __builtin_amdgcn_fdot2(hp.v, w0.v, o0, false);
        o1 = __builtin_amdgcn_fdot2(hp.v, w1.v, o1, false);
    }
#else
#pragma unroll
    for (int kk = 0; kk < 32; ++kk) {
        int pu = __shfl(hu, kk, 32);
        __half2 hv = *(__half2*)&pu;
        float2 hf = __half22float2(hv);
        float2 wa = __half22float2(sW2p[kk][2 * lane]);      // (W2[2kk][c0], W2[2kk+1][c0])
        float2 wb = __half22float2(sW2p[kk][2 * lane + 1]);
        o0 = fmaf(hf.x, wa.x, o0); o0 = fmaf(hf.y, wa.y, o0);
        o1 = fmaf(hf.x, wb.x, o1); o1 = fmaf(hf.y, wb.y, o1);
    }
#endif
    ((__half2*)out)[node * 32 + lane] = __floats2half2_rn(o0 * d, o1 * d);
}

// ---------------- layer-2 gather (logits fused; h written fp16 for pool) ----

__global__ void gather2_k(const __half* __restrict__ tS, const int* __restrict__ rowptr,
                          const int* __restrict__ col, const float* __restrict__ dinv,
                          const float* __restrict__ b, __half* __restrict__ out,
                          const float* __restrict__ Wa, const float* __restrict__ ba,
                          float* __restrict__ logits, int n) {
    int node = (int)((blockIdx.x * (size_t)blockDim.x + threadIdx.x) >> 5);
    int lane = threadIdx.x & 31;
    if (node >= n) return;
    int beg = rowptr[node], end = rowptr[node + 1];
    const __half2* tl = (const __half2*)tS + lane;
    float2 acc = __half22float2(tl[node * 32]);
    int e = beg;
    for (; e + 16 <= end; e += 16) {
        int s[16];
        __half2 v[16];
#pragma unroll
        for (int j = 0; j < 16; j++) s[j] = col[e + j];
#pragma unroll
        for (int j = 0; j < 16; j++) v[j] = tl[s[j] * 32];
        float2 t0 = make_float2(0.f, 0.f), t1 = make_float2(0.f, 0.f);
#pragma unroll
        for (int j = 0; j < 8; j++) {
            float2 f = __half22float2(v[j]);
            t0.x += f.x; t0.y += f.y;
        }
#pragma unroll
        for (int j = 8; j < 16; j++) {
            float2 f = __half22float2(v[j]);
            t1.x += f.x; t1.y += f.y;
        }
        acc.x += t0.x + t1.x;
        acc.y += t0.y + t1.y;
    }
    for (; e + 4 <= end; e += 4) {
        __half2 v0 = tl[col[e] * 32];
        __half2 v1 = tl[col[e + 1] * 32];
        __half2 v2 = tl[col[e + 2] * 32];
        __half2 v3 = tl[col[e + 3] * 32];
        float2 f0 = __half22float2(v0), f1 = __half22float2(v1);
        float2 f2 = __half22float2(v2), f3 = __half22float2(v3);
        acc.x += (f0.x + f1.x) + (f2.x + f3.x);
        acc.y += (f0.y + f1.y) + (f2.y + f3.y);
    }
    for (; e < end; ++e) {
        float2 f = __half22float2(tl[col[e] * 32]);
        acc.x += f.x; acc.y += f.y;
    }
    float d = dinv[node];
    float2 bb = *(const float2*)(b + 2 * lane);
    float h0 = fmaxf(fmaf(d, acc.x, bb.x), 0.0f);
    float h1 = fmaxf(fmaf(d, acc.y, bb.y), 0.0f);
    ((__half2*)out)[node * 32 + lane] = __floats2half2_rn(h0, h1);
    float2 wa = *(const float2*)(Wa + 2 * lane);
    float p = h0 * wa.x + h1 * wa.y;
#pragma unroll
    for (int off = 16; off > 0; off >>= 1) p += __shfl_down(p, off, 32);
    if (lane == 0) logits[node] = p + ba[0];
}

// ---------------- parallel mean-pool: 64 groups x 16 splits, branch-free ----

__global__ void pool2_k(const __half* __restrict__ h, const int* __restrict__ batch,
                        float* __restrict__ pooled, int n) {
    const int gid  = blockIdx.x / PSPLIT;
    const int part = blockIdx.x % PSPLIT;
    int lo = 0, hi = n;
    while (lo < hi) { int m = (lo + hi) >> 1; if (batch[m] < gid) lo = m + 1; else hi = m; }
    const int b0 = lo;
    hi = n;
    while (lo < hi) { int m = (lo + hi) >> 1; if (batch[m] < gid + 1) lo = m + 1; else hi = m; }
    const int b1 = lo;
    const int chunk = (b1 - b0 + PSPLIT - 1) / PSPLIT;
    const int r0 = b0 + part * chunk;
    const int r1 = min(r0 + chunk, b1);
    const int lane = threadIdx.x & 31;
    const int rg   = threadIdx.x >> 5;       // 8 rows in flight
    const __half2* hp = (const __half2*)h + lane;
    float2 acc = make_float2(0.f, 0.f);
    for (int i = r0 + rg; i < r1; i += 8) {
        float2 f = __half22float2(hp[(size_t)i * 32]);
        acc.x += f.x; acc.y += f.y;
    }
    __shared__ float2 red[8][32];
    red[rg][lane] = acc;
    __syncthreads();
    if (threadIdx.x < 32) {
        float2 s = make_float2(0.f, 0.f);
#pragma unroll
        for (int r = 0; r < 8; r++) { s.x += red[r][threadIdx.x].x; s.y += red[r][threadIdx.x].y; }
        atomicAdd(&pooled[gid * HID + 2 * threadIdx.x], s.x);
        atomicAdd(&pooled[gid * HID + 2 * threadIdx.x + 1], s.y);
    }
}

// ---------------- value head (counts via binary search on sorted batch) ----------------

__global__ void value_k(const float* __restrict__ pooled, const int* __restrict__ batch,
                        const float* __restrict__ Wc, const float* __restrict__ bc,
                        float* __restrict__ val, int n, int g) {
    int gw   = (int)((blockIdx.x * (size_t)blockDim.x + threadIdx.x) >> 6);
    int lane = threadIdx.x & 63;
    if (gw >= g) return;
    int lo = 0, hi = n;
    while (lo < hi) { int m = (lo + hi) >> 1; if (batch[m] < gw) lo = m + 1; else hi = m; }
    int b0 = lo;
    lo = 0; hi = n;
    while (lo < hi) { int m = (lo + hi) >> 1; if (batch[m] < gw + 1) lo = m + 1; else hi = m; }
    float cnt = fmaxf((float)(lo - b0), 1.0f);
    float p = (pooled[gw * HID + lane] / cnt) * Wc[lane];
#pragma unroll
    for (int off = 32; off > 0; off >>= 1) p += __shfl_down(p, off);
    if (lane == 0) val[gw] = p + bc[0];
}

extern "C" void kernel_launch(void* const* d_in, const int* in_sizes, int n_in,
                              void* d_out, int out_size, void* d_ws, size_t ws_size,
                              hipStream_t stream) {
    const float* x     = (const float*)d_in[0];
    const int*   ei    = (const int*)d_in[1];
    const int*   batch = (const int*)d_in[2];
    const float* W1    = (const float*)d_in[3];
    const float* b1    = (const float*)d_in[4];
    const float* W2    = (const float*)d_in[5];
    const float* b2    = (const float*)d_in[6];
    const float* Wa    = (const float*)d_in[7];
    const float* ba    = (const float*)d_in[8];
    const float* Wc    = (const float*)d_in[9];
    const float* bc    = (const float*)d_in[10];

    const int n = in_sizes[0] / FEAT;   // 100000
    const int e = in_sizes[1] / 2;      // 1600000
    const int g = out_size - n;         // 64
    const int* src = ei;
    const int* dst = ei + e;

    const int nb = (n + BNODES - 1) >> BSH;   // buckets (782)
    const int L  = nb * PB;                    // offset table length

    // workspace layout (packed aliases bufA: dead before first gemm)
    float*    ws     = (float*)d_ws;
    float*    dinv   = ws;                               // n
    float*    bufA   = dinv + n;                         // n*HID floats (tS1 fp16 / h2 fp16)
    float*    bufB   = bufA + (size_t)n * HID;           // n*HID floats (tS2 fp16)
    float*    pooled = bufB + (size_t)n * HID;           // g*HID
    int*      table  = (int*)(pooled + (size_t)g * HID); // L
    int*      aux    = table + L;                        // 1024
    int*      rowptr = aux + 1024;                       // n+1
    int*      col    = rowptr + n + 1;                   // e
    unsigned* packed = (unsigned*)bufA;                  // e (aliased, transient)
    __half*   tS1    = (__half*)bufA;                    // layer-1 transformed (after packed dead)
    __half*   tS2    = (__half*)bufB;                    // layer-2 transformed (gather1 output)
    __half*   h2     = (__half*)bufA;                    // layer-2 h (gather2 output, overwrites tS1)

    const int B = 256;
    const int gridT = (n + 63) / 64;
    const int gridG = (int)(((size_t)n * 32 + B - 1) / B);   // 32-lane group per node
    const int nb1   = (L + 1023) / 1024;

    (void)hipMemsetAsync(pooled, 0, (size_t)g * HID * sizeof(float), stream);

    // two-level CSR build: bucket partition -> in-bucket counting sort
    part_hist_k<<<PB, B, 0, stream>>>(dst, table, e, nb);
    scan1_k<<<nb1, 1024, 0, stream>>>(table, aux, L);
    scan2_k<<<1, 1024, 0, stream>>>(aux, nb1);
    part_scatter_k<<<PB, B, 0, stream>>>(src, dst, table, aux, packed, e, nb);
    bucket_sort_k<<<nb, B, 0, stream>>>(packed, table, aux, col, rowptr, dinv, n, e, nb);

    // layer 1 transform + gather (gather fuses h@W2*dinv -> tS2; gemm64 deleted)
    gemm_tile_k<<<gridT, B, 0, stream>>>(x, W1, dinv, tS1, n);
    gather1_k<<<gridG, B, 0, stream>>>(tS1, rowptr, col, dinv, b1, W2, tS2, n);

    // layer 2 gather (logits fused; h2 written for pool)
    gather2_k<<<gridG, B, 0, stream>>>(tS2, rowptr, col, dinv, b2, h2,
                                       Wa, ba, (float*)d_out, n);

    // heads
    pool2_k<<<g * PSPLIT, B, 0, stream>>>(h2, batch, pooled, n);
    value_k<<<(g * 64 + B - 1) / B, B, 0, stream>>>(pooled, batch, Wc, bc,
                                                    (float*)d_out + n, n, g);
}

// Round 9
// 296.610 us; speedup vs baseline: 1.1987x; 1.0228x over previous
//
#include <hip/hip_runtime.h>
#include <hip/hip_fp16.h>
#include <math.h>

#define FEAT 128
#define HID  64
#define BSH  7                 // 128 dst-nodes per bucket
#define BNODES (1 << BSH)
#define PB   256               // partition blocks (256: full-chip parallelism)
#define SRCM ((1u << 25) - 1)  // src in low 25 bits, dst_local in high 7
#define PSPLIT 16              // pool splits per group

typedef _Float16 f16_t;
typedef f16_t half8 __attribute__((ext_vector_type(8)));
typedef float  f32x4 __attribute__((ext_vector_type(4)));

// ---------------- stage 1: edge partition by dst-bucket ----------------

__global__ void part_hist_k(const int* __restrict__ dst, int* __restrict__ table,
                            int e, int nb) {
    __shared__ int lcnt[1024];
    for (int i = threadIdx.x; i < nb; i += 256) lcnt[i] = 0;
    __syncthreads();
    int eb = (e + PB - 1) / PB;
    int lo = blockIdx.x * eb, hi = min(lo + eb, e);
    for (int i = lo + threadIdx.x; i < hi; i += 256)
        atomicAdd(&lcnt[dst[i] >> BSH], 1);
    __syncthreads();
    for (int k = threadIdx.x; k < nb; k += 256)
        table[k * PB + blockIdx.x] = lcnt[k];
}

__global__ void scan1_k(int* __restrict__ data, int* __restrict__ aux, int L) {
    __shared__ int s[1024];
    int gid = blockIdx.x * 1024 + threadIdx.x;
    int v = (gid < L) ? data[gid] : 0;
    s[threadIdx.x] = v;
    __syncthreads();
    for (int off = 1; off < 1024; off <<= 1) {
        int t = (threadIdx.x >= off) ? s[threadIdx.x - off] : 0;
        __syncthreads();
        s[threadIdx.x] += t;
        __syncthreads();
    }
    if (gid < L) data[gid] = s[threadIdx.x] - v;            // exclusive in block
    if (threadIdx.x == 1023) aux[blockIdx.x] = s[1023];     // block total
}

__global__ void scan2_k(int* aux, int naux) {
    __shared__ int s[1024];
    int v = (threadIdx.x < naux) ? aux[threadIdx.x] : 0;
    s[threadIdx.x] = v;
    __syncthreads();
    for (int off = 1; off < 1024; off <<= 1) {
        int t = (threadIdx.x >= off) ? s[threadIdx.x - off] : 0;
        __syncthreads();
        s[threadIdx.x] += t;
        __syncthreads();
    }
    if (threadIdx.x < naux) aux[threadIdx.x] = s[threadIdx.x] - v;
}

__global__ void part_scatter_k(const int* __restrict__ src, const int* __restrict__ dst,
                               const int* __restrict__ table, const int* __restrict__ aux,
                               unsigned* __restrict__ packed, int e, int nb) {
    __shared__ int loff[1024];
    for (int k = threadIdx.x; k < nb; k += 256) {
        int idx = k * PB + blockIdx.x;
        loff[k] = table[idx] + aux[idx >> 10];
    }
    __syncthreads();
    int eb = (e + PB - 1) / PB;
    int lo = blockIdx.x * eb, hi = min(lo + eb, e);
    for (int i = lo + threadIdx.x; i < hi; i += 256) {
        int d = dst[i];
        int p = atomicAdd(&loff[d >> BSH], 1);
        packed[p] = ((unsigned)(d & (BNODES - 1)) << 25) | (unsigned)src[i];
    }
}

// ---------------- stage 2: per-bucket counting sort -> per-node CSR + dinv ----

__global__ void bucket_sort_k(const unsigned* __restrict__ packed,
                              const int* __restrict__ table, const int* __restrict__ aux,
                              int* __restrict__ col, int* __restrict__ rowptr,
                              float* __restrict__ dinv, int n, int e, int nb) {
    __shared__ int cnt[BNODES];
    __shared__ int s[BNODES];
    __shared__ int cur[BNODES];
    const int k = blockIdx.x;
    const int t = threadIdx.x;
    if (t < BNODES) cnt[t] = 0;
    __syncthreads();
    int i0 = k * PB;
    int i1 = (k + 1) * PB;
    const int bs = table[i0] + aux[i0 >> 10];
    const int be = (k + 1 < nb) ? (table[i1] + aux[i1 >> 10]) : e;
    for (int i = bs + t; i < be; i += 256)
        atomicAdd(&cnt[packed[i] >> 25], 1);
    __syncthreads();
    if (t < BNODES) s[t] = cnt[t];
    __syncthreads();
    for (int off = 1; off < BNODES; off <<= 1) {
        int v = (t < BNODES && t >= off) ? s[t - off] : 0;
        __syncthreads();
        if (t < BNODES) s[t] += v;
        __syncthreads();
    }
    if (t < BNODES) {
        int base = bs + s[t] - cnt[t];
        cur[t] = base;
        int node = (k << BSH) + t;
        if (node < n) {
            rowptr[node] = base;
            dinv[node] = 1.0f / sqrtf(1.0f + (float)cnt[t]);
            if (node == n - 1) rowptr[n] = base + cnt[t];
        }
    }
    __syncthreads();
    for (int i = bs + t; i < be; i += 256) {
        unsigned u = packed[i];
        int p = atomicAdd(&cur[u >> 25], 1);
        col[p] = (int)(u & SRCM);
    }
}

// ---------------- dense transform: out[n,64] = fp16((X[n,128] @ W1) * dinv[row]) ----

__global__ __launch_bounds__(256, 3)
void gemm_tile_k(const float* __restrict__ X, const float* __restrict__ W,
                 const float* __restrict__ dinv, __half* __restrict__ out, int n) {
    constexpr int K = FEAT;
    __shared__ float sX[64][K + 4];
    __shared__ float sW[64][64];       // one 64-row slab of W
    const int row0 = blockIdx.x * 64;
    const int t  = threadIdx.x;
    const int tx = t & 15;
    const int ty = t >> 4;

    const float* xb = X + (size_t)row0 * K;
#pragma unroll
    for (int it = 0; it < K / 16; ++it) {
        int fl = it * 1024 + t * 4;
        int r  = fl >> 7;
        int k  = fl & (K - 1);
        float4 v = make_float4(0.f, 0.f, 0.f, 0.f);
        if (row0 + r < n) v = *(const float4*)(xb + fl);
        *(float4*)&sX[r][k] = v;
    }

    float acc[4][4] = {};
#pragma unroll
    for (int ph = 0; ph < K / 64; ++ph) {
        __syncthreads();
#pragma unroll
        for (int it = 0; it < 4; ++it) {
            int fl = it * 1024 + t * 4;
            *(float4*)&sW[fl >> 6][fl & 63] = *(const float4*)(W + ph * 64 * HID + fl);
        }
        __syncthreads();

#pragma unroll 8
        for (int k = 0; k < 64; k += 4) {
            float4 a[4], b[4];
#pragma unroll
            for (int i = 0; i < 4; i++) a[i] = *(float4*)&sX[ty * 4 + i][ph * 64 + k];
#pragma unroll
            for (int j = 0; j < 4; j++) b[j] = *(float4*)&sW[k + j][tx * 4];
#pragma unroll
            for (int i = 0; i < 4; i++) {
                acc[i][0] = fmaf(a[i].x, b[0].x, acc[i][0]);
                acc[i][1] = fmaf(a[i].x, b[0].y, acc[i][1]);
                acc[i][2] = fmaf(a[i].x, b[0].z, acc[i][2]);
                acc[i][3] = fmaf(a[i].x, b[0].w, acc[i][3]);
                acc[i][0] = fmaf(a[i].y, b[1].x, acc[i][0]);
                acc[i][1] = fmaf(a[i].y, b[1].y, acc[i][1]);
                acc[i][2] = fmaf(a[i].y, b[1].z, acc[i][2]);
                acc[i][3] = fmaf(a[i].y, b[1].w, acc[i][3]);
                acc[i][0] = fmaf(a[i].z, b[2].x, acc[i][0]);
                acc[i][1] = fmaf(a[i].z, b[2].y, acc[i][1]);
                acc[i][2] = fmaf(a[i].z, b[2].z, acc[i][2]);
                acc[i][3] = fmaf(a[i].z, b[2].w, acc[i][3]);
                acc[i][0] = fmaf(a[i].w, b[3].x, acc[i][0]);
                acc[i][1] = fmaf(a[i].w, b[3].y, acc[i][1]);
                acc[i][2] = fmaf(a[i].w, b[3].z, acc[i][2]);
                acc[i][3] = fmaf(a[i].w, b[3].w, acc[i][3]);
            }
        }
    }

#pragma unroll
    for (int i = 0; i < 4; i++) {
        int gr = row0 + ty * 4 + i;
        if (gr < n) {
            float sc = dinv[gr];
            union { __half2 h[2]; unsigned long long u; } pk;
            pk.h[0] = __floats2half2_rn(acc[i][0] * sc, acc[i][1] * sc);
            pk.h[1] = __floats2half2_rn(acc[i][2] * sc, acc[i][3] * sc);
            *(unsigned long long*)(out + (size_t)gr * HID + tx * 4) = pk.u;
        }
    }
}

// ---------------- layer-1 gather (plain; fp16 h output) ----------------

__global__ void gather1_k(const __half* __restrict__ tS, const int* __restrict__ rowptr,
                          const int* __restrict__ col, const float* __restrict__ dinv,
                          const float* __restrict__ b, __half* __restrict__ out, int n) {
    int node = (int)((blockIdx.x * (size_t)blockDim.x + threadIdx.x) >> 5);
    int lane = threadIdx.x & 31;
    if (node >= n) return;
    int beg = rowptr[node], end = rowptr[node + 1];
    const __half2* tl = (const __half2*)tS + lane;   // row stride = 32 half2
    float2 acc = __half22float2(tl[node * 32]);      // self-loop term
    int e = beg;
    for (; e + 16 <= end; e += 16) {
        int s[16];
        __half2 v[16];
#pragma unroll
        for (int j = 0; j < 16; j++) s[j] = col[e + j];
#pragma unroll
        for (int j = 0; j < 16; j++) v[j] = tl[s[j] * 32];
        float2 t0 = make_float2(0.f, 0.f), t1 = make_float2(0.f, 0.f);
#pragma unroll
        for (int j = 0; j < 8; j++) {
            float2 f = __half22float2(v[j]);
            t0.x += f.x; t0.y += f.y;
        }
#pragma unroll
        for (int j = 8; j < 16; j++) {
            float2 f = __half22float2(v[j]);
            t1.x += f.x; t1.y += f.y;
        }
        acc.x += t0.x + t1.x;
        acc.y += t0.y + t1.y;
    }
    for (; e + 4 <= end; e += 4) {
        __half2 v0 = tl[col[e] * 32];
        __half2 v1 = tl[col[e + 1] * 32];
        __half2 v2 = tl[col[e + 2] * 32];
        __half2 v3 = tl[col[e + 3] * 32];
        float2 f0 = __half22float2(v0), f1 = __half22float2(v1);
        float2 f2 = __half22float2(v2), f3 = __half22float2(v3);
        acc.x += (f0.x + f1.x) + (f2.x + f3.x);
        acc.y += (f0.y + f1.y) + (f2.y + f3.y);
    }
    for (; e < end; ++e) {
        float2 f = __half22float2(tl[col[e] * 32]);
        acc.x += f.x; acc.y += f.y;
    }
    float d = dinv[node];
    float2 bb = *(const float2*)(b + 2 * lane);
    float h0 = fmaxf(fmaf(d, acc.x, bb.x), 0.0f);
    float h1 = fmaxf(fmaf(d, acc.y, bb.y), 0.0f);
    ((__half2*)out)[node * 32 + lane] = __floats2half2_rn(h0, h1);
}

// ---------------- t2: tS2[n,64] = fp16((h16 @ W2) * dinv) via MFMA 16x16x32 f16 ----
// One wave per 16-row strip. B-frags (all of W2, fp16) built once per wave in
// registers — amortizes W2 access over the strip (the fused-epilogue version
// re-read 8KB of W2 per NODE through LDS; that was the 22us).
// Fragment maps (guide-verified family): A: row=lane&15, k=(lane>>4)*8+j;
// B: k=(lane>>4)*8+j, col=lane&15; C/D: col=lane&15, row=(lane>>4)*4+reg.

__global__ __launch_bounds__(256)
void t2_k(const __half* __restrict__ h, const float* __restrict__ W2,
          const float* __restrict__ dinv, __half* __restrict__ out, int n) {
    const int wave  = threadIdx.x >> 6;
    const int l     = threadIdx.x & 63;
    const int strip = blockIdx.x * 4 + wave;
    const int r0    = strip * 16;
    if (r0 >= n) return;
    const int col = l & 15;
    const int kb  = l >> 4;          // 0..3

    // B-frags: bf[t][kk][j] = W2[kk*32 + kb*8 + j][t*16 + col]  (fp32 -> fp16)
    half8 bf[4][2];
#pragma unroll
    for (int t = 0; t < 4; ++t)
#pragma unroll
        for (int kk = 0; kk < 2; ++kk)
#pragma unroll
            for (int j = 0; j < 8; ++j)
                bf[t][kk][j] = (f16_t)W2[(kk * 32 + kb * 8 + j) * HID + t * 16 + col];

    // A-frags: contiguous 16B loads of the h row
    const int arow = r0 + col;       // row = lane&15
    const __half* ap = h + (size_t)arow * HID + kb * 8;
    half8 a0 = *(const half8*)(ap);
    half8 a1 = *(const half8*)(ap + 32);

    f32x4 acc[4] = {};
#pragma unroll
    for (int t = 0; t < 4; ++t) {
        acc[t] = __builtin_amdgcn_mfma_f32_16x16x32_f16(a0, bf[t][0], acc[t], 0, 0, 0);
        acc[t] = __builtin_amdgcn_mfma_f32_16x16x32_f16(a1, bf[t][1], acc[t], 0, 0, 0);
    }

    // epilogue: lane holds cols {col+16t}, rows r0 + kb*4 + r
    const int rbase = r0 + kb * 4;
#pragma unroll
    for (int r = 0; r < 4; ++r) {
        int gr = rbase + r;
        if (gr < n) {
            float dv = dinv[gr];
#pragma unroll
            for (int t = 0; t < 4; ++t)
                out[(size_t)gr * HID + t * 16 + col] = __float2half(acc[t][r] * dv);
        }
    }
}

// ---------------- layer-2 gather (logits fused; h written fp16 for pool) ----

__global__ void gather2_k(const __half* __restrict__ tS, const int* __restrict__ rowptr,
                          const int* __restrict__ col, const float* __restrict__ dinv,
                          const float* __restrict__ b, __half* __restrict__ out,
                          const float* __restrict__ Wa, const float* __restrict__ ba,
                          float* __restrict__ logits, int n) {
    int node = (int)((blockIdx.x * (size_t)blockDim.x + threadIdx.x) >> 5);
    int lane = threadIdx.x & 31;
    if (node >= n) return;
    int beg = rowptr[node], end = rowptr[node + 1];
    const __half2* tl = (const __half2*)tS + lane;
    float2 acc = __half22float2(tl[node * 32]);
    int e = beg;
    for (; e + 16 <= end; e += 16) {
        int s[16];
        __half2 v[16];
#pragma unroll
        for (int j = 0; j < 16; j++) s[j] = col[e + j];
#pragma unroll
        for (int j = 0; j < 16; j++) v[j] = tl[s[j] * 32];
        float2 t0 = make_float2(0.f, 0.f), t1 = make_float2(0.f, 0.f);
#pragma unroll
        for (int j = 0; j < 8; j++) {
            float2 f = __half22float2(v[j]);
            t0.x += f.x; t0.y += f.y;
        }
#pragma unroll
        for (int j = 8; j < 16; j++) {
            float2 f = __half22float2(v[j]);
            t1.x += f.x; t1.y += f.y;
        }
        acc.x += t0.x + t1.x;
        acc.y += t0.y + t1.y;
    }
    for (; e + 4 <= end; e += 4) {
        __half2 v0 = tl[col[e] * 32];
        __half2 v1 = tl[col[e + 1] * 32];
        __half2 v2 = tl[col[e + 2] * 32];
        __half2 v3 = tl[col[e + 3] * 32];
        float2 f0 = __half22float2(v0), f1 = __half22float2(v1);
        float2 f2 = __half22float2(v2), f3 = __half22float2(v3);
        acc.x += (f0.x + f1.x) + (f2.x + f3.x);
        acc.y += (f0.y + f1.y) + (f2.y + f3.y);
    }
    for (; e < end; ++e) {
        float2 f = __half22float2(tl[col[e] * 32]);
        acc.x += f.x; acc.y += f.y;
    }
    float d = dinv[node];
    float2 bb = *(const float2*)(b + 2 * lane);
    float h0 = fmaxf(fmaf(d, acc.x, bb.x), 0.0f);
    float h1 = fmaxf(fmaf(d, acc.y, bb.y), 0.0f);
    ((__half2*)out)[node * 32 + lane] = __floats2half2_rn(h0, h1);
    float2 wa = *(const float2*)(Wa + 2 * lane);
    float p = h0 * wa.x + h1 * wa.y;
#pragma unroll
    for (int off = 16; off > 0; off >>= 1) p += __shfl_down(p, off, 32);
    if (lane == 0) logits[node] = p + ba[0];
}

// ---------------- parallel mean-pool: 64 groups x 16 splits, branch-free ----

__global__ void pool2_k(const __half* __restrict__ h, const int* __restrict__ batch,
                        float* __restrict__ pooled, int n) {
    const int gid  = blockIdx.x / PSPLIT;
    const int part = blockIdx.x % PSPLIT;
    int lo = 0, hi = n;
    while (lo < hi) { int m = (lo + hi) >> 1; if (batch[m] < gid) lo = m + 1; else hi = m; }
    const int b0 = lo;
    hi = n;
    while (lo < hi) { int m = (lo + hi) >> 1; if (batch[m] < gid + 1) lo = m + 1; else hi = m; }
    const int b1 = lo;
    const int chunk = (b1 - b0 + PSPLIT - 1) / PSPLIT;
    const int r0 = b0 + part * chunk;
    const int r1 = min(r0 + chunk, b1);
    const int lane = threadIdx.x & 31;
    const int rg   = threadIdx.x >> 5;       // 8 rows in flight
    const __half2* hp = (const __half2*)h + lane;
    float2 acc = make_float2(0.f, 0.f);
    for (int i = r0 + rg; i < r1; i += 8) {
        float2 f = __half22float2(hp[(size_t)i * 32]);
        acc.x += f.x; acc.y += f.y;
    }
    __shared__ float2 red[8][32];
    red[rg][lane] = acc;
    __syncthreads();
    if (threadIdx.x < 32) {
        float2 s = make_float2(0.f, 0.f);
#pragma unroll
        for (int r = 0; r < 8; r++) { s.x += red[r][threadIdx.x].x; s.y += red[r][threadIdx.x].y; }
        atomicAdd(&pooled[gid * HID + 2 * threadIdx.x], s.x);
        atomicAdd(&pooled[gid * HID + 2 * threadIdx.x + 1], s.y);
    }
}

// ---------------- value head (counts via binary search on sorted batch) ----------------

__global__ void value_k(const float* __restrict__ pooled, const int* __restrict__ batch,
                        const float* __restrict__ Wc, const float* __restrict__ bc,
                        float* __restrict__ val, int n, int g) {
    int gw   = (int)((blockIdx.x * (size_t)blockDim.x + threadIdx.x) >> 6);
    int lane = threadIdx.x & 63;
    if (gw >= g) return;
    int lo = 0, hi = n;
    while (lo < hi) { int m = (lo + hi) >> 1; if (batch[m] < gw) lo = m + 1; else hi = m; }
    int b0 = lo;
    lo = 0; hi = n;
    while (lo < hi) { int m = (lo + hi) >> 1; if (batch[m] < gw + 1) lo = m + 1; else hi = m; }
    float cnt = fmaxf((float)(lo - b0), 1.0f);
    float p = (pooled[gw * HID + lane] / cnt) * Wc[lane];
#pragma unroll
    for (int off = 32; off > 0; off >>= 1) p += __shfl_down(p, off);
    if (lane == 0) val[gw] = p + bc[0];
}

extern "C" void kernel_launch(void* const* d_in, const int* in_sizes, int n_in,
                              void* d_out, int out_size, void* d_ws, size_t ws_size,
                              hipStream_t stream) {
    const float* x     = (const float*)d_in[0];
    const int*   ei    = (const int*)d_in[1];
    const int*   batch = (const int*)d_in[2];
    const float* W1    = (const float*)d_in[3];
    const float* b1    = (const float*)d_in[4];
    const float* W2    = (const float*)d_in[5];
    const float* b2    = (const float*)d_in[6];
    const float* Wa    = (const float*)d_in[7];
    const float* ba    = (const float*)d_in[8];
    const float* Wc    = (const float*)d_in[9];
    const float* bc    = (const float*)d_in[10];

    const int n = in_sizes[0] / FEAT;   // 100000
    const int e = in_sizes[1] / 2;      // 1600000
    const int g = out_size - n;         // 64
    const int* src = ei;
    const int* dst = ei + e;

    const int nb = (n + BNODES - 1) >> BSH;   // buckets (782)
    const int L  = nb * PB;                    // offset table length

    // workspace layout (packed aliases bufA: dead before first gemm)
    float*    ws     = (float*)d_ws;
    float*    dinv   = ws;                               // n
    float*    bufA   = dinv + n;                         // n*HID floats (tS1 / tS2 fp16)
    float*    bufB   = bufA + (size_t)n * HID;           // n*HID floats (h16 / h2 fp16)
    float*    pooled = bufB + (size_t)n * HID;           // g*HID
    int*      table  = (int*)(pooled + (size_t)g * HID); // L
    int*      aux    = table + L;                        // 1024
    int*      rowptr = aux + 1024;                       // n+1
    int*      col    = rowptr + n + 1;                   // e
    unsigned* packed = (unsigned*)bufA;                  // e (aliased, transient)
    __half*   tS1    = (__half*)bufA;                    // layer-1 transformed
    __half*   h16    = (__half*)bufB;                    // layer-1 h (gather1 out)
    __half*   tS2    = (__half*)bufA;                    // layer-2 transformed (t2 out, tS1 dead)
    __half*   h2     = (__half*)bufB;                    // layer-2 h (gather2 out, h16 dead)

    const int B = 256;
    const int gridT  = (n + 63) / 64;
    const int gridG  = (int)(((size_t)n * 32 + B - 1) / B);  // 32-lane group per node
    const int strips = (n + 15) / 16;
    const int gridT2 = (strips + 3) / 4;                      // 4 waves/block, 1 strip/wave
    const int nb1    = (L + 1023) / 1024;

    (void)hipMemsetAsync(pooled, 0, (size_t)g * HID * sizeof(float), stream);

    // two-level CSR build: bucket partition -> in-bucket counting sort
    part_hist_k<<<PB, B, 0, stream>>>(dst, table, e, nb);
    scan1_k<<<nb1, 1024, 0, stream>>>(table, aux, L);
    scan2_k<<<1, 1024, 0, stream>>>(aux, nb1);
    part_scatter_k<<<PB, B, 0, stream>>>(src, dst, table, aux, packed, e, nb);
    bucket_sort_k<<<nb, B, 0, stream>>>(packed, table, aux, col, rowptr, dinv, n, e, nb);

    // layer 1: dense transform + gather
    gemm_tile_k<<<gridT, B, 0, stream>>>(x, W1, dinv, tS1, n);
    gather1_k<<<gridG, B, 0, stream>>>(tS1, rowptr, col, dinv, b1, h16, n);

    // layer-2 transform via MFMA, then gather (logits fused)
    t2_k<<<gridT2, B, 0, stream>>>(h16, W2, dinv, tS2, n);
    gather2_k<<<gridG, B, 0, stream>>>(tS2, rowptr, col, dinv, b2, h2,
                                       Wa, ba, (float*)d_out, n);

    // heads
    pool2_k<<<g * PSPLIT, B, 0, stream>>>(h2, batch, pooled, n);
    value_k<<<(g * 64 + B - 1) / B, B, 0, stream>>>(pooled, batch, Wc, bc,
                                                    (float*)d_out + n, n, g);
}